// Round 1
// 1055.396 us; speedup vs baseline: 1.3941x; 1.3941x over previous
//
#include <hip/hip_runtime.h>
#include <hip/hip_bf16.h>

// RGAT pipeline for MI355X. Inputs f32, OUTPUTS f32 (round-6 analysis: the
// 1.80078125 error decomposes exactly as a bf16-halfword misread of an f32
// buffer; harness reads d_out as f32, bf16 appears only in its ref-rounding).
// Scratch (81.4 MB) lives in d_out's f32 adj region (144 MB), all dead before
// adj_kernel, which reads mu from out_mu (disjoint from the adj range it
// writes). d_ws and d_in are untouched.
//
// R1 change: agg_kernel rewritten as flash-style online-softmax with
// lane-parallel logit computation (1x el gather + 1x exp per edge instead of
// 3x) and a 4/8-edge-per-iteration vectorized float4 gather phase using
// register shuffles for (src, weight) broadcast. No LDS / no barriers in the
// relation loop. Padded lanes carry w=0, s=0 so all shuffles read active
// lanes and contribute exactly zero.

static constexpr int N_  = 20000;
static constexpr int R_  = 3;
static constexpr int E_  = 200000;
static constexpr int NB1 = 6000;   // N1 == N2 == 6000

__device__ __forceinline__ float sigmoidf_(float x) {
  return 1.0f / (1.0f + __expf(-x));
}

// ---------------- CSR build ----------------
__global__ void hist_kernel(const int* __restrict__ dst, int* __restrict__ counts) {
  int i = blockIdx.x * blockDim.x + threadIdx.x;
  if (i >= R_ * E_) return;
  int r = i / E_;
  atomicAdd(&counts[r * N_ + dst[i]], 1);
}

__global__ void scan_kernel(const int* __restrict__ counts, int* __restrict__ ptr) {
  int r = blockIdx.x;
  __shared__ int buf[1024];
  __shared__ int carry;
  int tid = threadIdx.x;
  if (tid == 0) carry = 0;
  __syncthreads();
  for (int base = 0; base < N_; base += 1024) {
    int i = base + tid;
    int v = (i < N_) ? counts[r * N_ + i] : 0;
    buf[tid] = v;
    __syncthreads();
    for (int off = 1; off < 1024; off <<= 1) {
      int t = (tid >= off) ? buf[tid - off] : 0;
      __syncthreads();
      buf[tid] += t;
      __syncthreads();
    }
    int c = carry;
    if (i < N_) ptr[r * (N_ + 1) + i] = c + buf[tid] - v;  // exclusive scan
    __syncthreads();
    if (tid == 1023) carry = c + buf[1023];
    __syncthreads();
  }
  if (tid == 0) ptr[r * (N_ + 1) + N_] = carry;
}

__global__ void scatter_kernel(const int* __restrict__ src, const int* __restrict__ dst,
                               const int* __restrict__ ptr, int* __restrict__ fill,
                               int* __restrict__ csrc) {
  int i = blockIdx.x * blockDim.x + threadIdx.x;
  if (i >= R_ * E_) return;
  int r = i / E_;
  int d = dst[i];
  int pos = ptr[r * (N_ + 1) + d] + atomicAdd(&fill[r * N_ + d], 1);
  csrc[r * E_ + pos] = src[i];
}

// ---------------- GEMM + fused attention-logit epilogue ----------------
// h[r][n][HF] = A[n][:] @ W[r][:][:] (f32); el/er[r][n][hh] = sum_f h*al/ar.
// 256 threads = 16x16, tile 64 nodes x 64 cols, 4x4 register blocking.
template <int DIN, int HF, int H, int F>
__global__ __launch_bounds__(256) void gemm_el_kernel(
    const float* __restrict__ A, const float* __restrict__ W,
    const float* __restrict__ al, const float* __restrict__ ar,
    float* __restrict__ h, float* __restrict__ el, float* __restrict__ er) {
  __shared__ float sAT[64][68];  // [k][node]
  __shared__ float sW[64][68];   // [k][col]
  const int nb  = blockIdx.x * 64;
  const int cg  = blockIdx.y;    // 64-col group
  const int r   = blockIdx.z;
  const int tid = threadIdx.x;
  const int ty  = tid >> 4, tx = tid & 15;

  float acc[4][4];
#pragma unroll
  for (int i = 0; i < 4; ++i)
#pragma unroll
    for (int j = 0; j < 4; ++j) acc[i][j] = 0.f;

  for (int k0 = 0; k0 < DIN; k0 += 64) {
    for (int idx = tid; idx < 4096; idx += 256) {
      int nl = idx >> 6, kk = idx & 63;
      int n = nb + nl;
      sAT[kk][nl] = (n < N_) ? A[(size_t)n * DIN + k0 + kk] : 0.f;
    }
    for (int idx = tid; idx < 4096; idx += 256) {
      int kk = idx >> 6, cl = idx & 63;
      sW[kk][cl] = W[((size_t)r * DIN + k0 + kk) * HF + cg * 64 + cl];
    }
    __syncthreads();
#pragma unroll 8
    for (int kk = 0; kk < 64; ++kk) {
      const float4 a4 = *(const float4*)&sAT[kk][ty * 4];
      const float4 w4 = *(const float4*)&sW[kk][tx * 4];
      const float a[4] = {a4.x, a4.y, a4.z, a4.w};
      const float w[4] = {w4.x, w4.y, w4.z, w4.w};
#pragma unroll
      for (int i = 0; i < 4; ++i)
#pragma unroll
        for (int j = 0; j < 4; ++j) acc[i][j] = fmaf(a[i], w[j], acc[i][j]);
    }
    __syncthreads();
  }

  // store h (float4 per row)
  const int c0 = cg * 64 + tx * 4;
#pragma unroll
  for (int i = 0; i < 4; ++i) {
    int n = nb + ty * 4 + i;
    if (n < N_) {
      float4 v; v.x = acc[i][0]; v.y = acc[i][1]; v.z = acc[i][2]; v.w = acc[i][3];
      *(float4*)&h[((size_t)r * N_ + n) * HF + c0] = v;
    }
  }

  // fused el/er: reduce over f within head via shuffles (group width G = F/4)
  const int hh = c0 / F;
  const int f0 = c0 % F;
  float al4[4], ar4[4];
#pragma unroll
  for (int j = 0; j < 4; ++j) {
    al4[j] = al[((size_t)r * H + hh) * F + f0 + j];
    ar4[j] = ar[((size_t)r * H + hh) * F + f0 + j];
  }
  float elp[4], erp[4];
#pragma unroll
  for (int i = 0; i < 4; ++i) {
    elp[i] = acc[i][0] * al4[0] + acc[i][1] * al4[1] + acc[i][2] * al4[2] + acc[i][3] * al4[3];
    erp[i] = acc[i][0] * ar4[0] + acc[i][1] * ar4[1] + acc[i][2] * ar4[2] + acc[i][3] * ar4[3];
  }
  constexpr int G = F / 4;  // tx-threads per head: 16 (F=64) or 8 (F=32)
#pragma unroll
  for (int off = G / 2; off >= 1; off >>= 1) {
#pragma unroll
    for (int i = 0; i < 4; ++i) {
      elp[i] += __shfl_down(elp[i], off, G);
      erp[i] += __shfl_down(erp[i], off, G);
    }
  }
  if ((tx & (G - 1)) == 0) {
#pragma unroll
    for (int i = 0; i < 4; ++i) {
      int n = nb + ty * 4 + i;
      if (n < N_) {
        el[((size_t)r * N_ + n) * H + hh] = elp[i];
        er[((size_t)r * N_ + n) * H + hh] = erp[i];
      }
    }
  }
}

// ---------------- Per-destination edge softmax + aggregation ----------------
// One block per node; wave = head. Flash-style online softmax per 64-edge
// chunk: lane-parallel logits (one el gather + one exp per edge), then a
// vectorized gather phase processing EPG edges per iteration with float4
// h-row loads; (src, w) broadcast via register shuffles. Accumulate over R
// relations (f32), then head-mean + activation + optional base add.
template <int H, int F, bool RELU>
__global__ __launch_bounds__(256) void agg_kernel(
    const float* __restrict__ h, const float* __restrict__ el, const float* __restrict__ er,
    const int* __restrict__ ptr, const int* __restrict__ srcs,
    const float* __restrict__ base, float* __restrict__ outf) {
  constexpr int VL  = F / 4;    // lanes per edge-row (float4 granules): 16 or 8
  constexpr int EPG = 64 / VL;  // edges per wave-iteration: 4 or 8
  const int n    = blockIdx.x;
  const int wave = threadIdx.x >> 6;   // = head
  const int lane = threadIdx.x & 63;
  const int eg   = lane / VL;          // edge slot within iteration
  const int fl   = lane % VL;          // float4 index within row

  float4 tot = {0.f, 0.f, 0.f, 0.f};

  for (int r = 0; r < R_; ++r) {
    const int p0  = ptr[r * (N_ + 1) + n];
    const int deg = ptr[r * (N_ + 1) + n + 1] - p0;
    if (deg == 0) continue;
    const int* sp = srcs + (size_t)r * E_ + p0;
    const float erv = er[((size_t)r * N_ + n) * H + wave];

    float m = -3.0e38f, dsum = 0.f;
    float4 racc = {0.f, 0.f, 0.f, 0.f};

    for (int b0 = 0; b0 < deg; b0 += 64) {
      const int cnt = min(64, deg - b0);
      int   s = 0;
      float e = -3.0e38f;
      if (lane < cnt) {
        s = sp[b0 + lane];
        e = el[((size_t)r * N_ + s) * H + wave] + erv;
        e = (e > 0.f) ? e : 0.2f * e;
      }
      // chunk max (butterfly; all lanes end with the max)
      float mloc = e;
#pragma unroll
      for (int off = 32; off >= 1; off >>= 1)
        mloc = fmaxf(mloc, __shfl_xor(mloc, off, 64));
      const float mnew  = fmaxf(m, mloc);
      const float scale = __expf(m - mnew);   // 0 on first chunk (m = -3e38)
      const float w = __expf(e - mnew);       // exactly 0 for padded lanes
      float wsum = w;
#pragma unroll
      for (int off = 32; off >= 1; off >>= 1)
        wsum += __shfl_xor(wsum, off, 64);
      dsum = fmaf(dsum, scale, wsum);
      racc.x *= scale; racc.y *= scale; racc.z *= scale; racc.w *= scale;
      m = mnew;

      // gather: uniform trip count; padded slots have w=0, s=0 (safe load)
      const int kmax = (cnt + EPG - 1) / EPG;
      for (int k = 0; k < kmax; ++k) {
        const int i2 = eg + k * EPG;          // < 64 always
        const int   s2 = __shfl(s, i2, 64);
        const float w2 = __shfl(w, i2, 64);
        const float4 hv =
            *(const float4*)&h[((size_t)r * N_ + s2) * (H * F) + wave * F + fl * 4];
        racc.x = fmaf(w2, hv.x, racc.x);
        racc.y = fmaf(w2, hv.y, racc.y);
        racc.z = fmaf(w2, hv.z, racc.z);
        racc.w = fmaf(w2, hv.w, racc.w);
      }
    }
    const float inv = 1.0f / (dsum + 1e-16f);
    tot.x = fmaf(racc.x, inv, tot.x);
    tot.y = fmaf(racc.y, inv, tot.y);
    tot.z = fmaf(racc.z, inv, tot.z);
    tot.w = fmaf(racc.w, inv, tot.w);
  }

  // reduce across edge-groups (xor butterfly over offsets VL..32)
#pragma unroll
  for (int off = VL; off < 64; off <<= 1) {
    tot.x += __shfl_xor(tot.x, off, 64);
    tot.y += __shfl_xor(tot.y, off, 64);
    tot.z += __shfl_xor(tot.z, off, 64);
    tot.w += __shfl_xor(tot.w, off, 64);
  }

  __shared__ float4 sh4[H][VL];
  if (eg == 0) sh4[wave][fl] = tot;
  __syncthreads();
  if (threadIdx.x < VL) {
    float4 v = sh4[0][threadIdx.x];
#pragma unroll
    for (int hh = 1; hh < H; ++hh) {
      float4 u = sh4[hh][threadIdx.x];
      v.x += u.x; v.y += u.y; v.z += u.z; v.w += u.w;
    }
    const float sc = 1.0f / H;
    v.x *= sc; v.y *= sc; v.z *= sc; v.w *= sc;
    if (RELU) {
      v.x = fmaxf(v.x, 0.f); v.y = fmaxf(v.y, 0.f);
      v.z = fmaxf(v.z, 0.f); v.w = fmaxf(v.w, 0.f);
    }
    if (base) {
      float4 bv = *(const float4*)&base[(size_t)n * F + threadIdx.x * 4];
      v.x += bv.x; v.y += bv.y; v.z += bv.z; v.w += bv.w;
    }
    *(float4*)&outf[(size_t)n * F + threadIdx.x * 4] = v;
  }
}

// ---------------- adj = mean_s sigmoid(z1[s] @ z2[s]^T) ----------------
// Reads f32 mu from out_mu (d_out elements [36M,37.28M)) and writes only the
// adj range [0,36M) -- disjoint, no hazard. 256 threads = 16x16, tile 128x128,
// 8x8 register blocking, s staged via LDS.
__global__ __launch_bounds__(256) void adj_kernel(const float* __restrict__ mu,
                                                  float* __restrict__ out) {
  __shared__ float sA[32][132];  // [d][i_local]
  __shared__ float sB[32][132];  // [d][j_local]
  const int jb = blockIdx.x * 128;
  const int ib = blockIdx.y * 128;
  const int tid = threadIdx.x;
  const int ty = tid >> 4, tx = tid & 15;

  float res[8][8];
#pragma unroll
  for (int i = 0; i < 8; ++i)
#pragma unroll
    for (int j = 0; j < 8; ++j) res[i][j] = 0.f;

  for (int s = 0; s < 2; ++s) {
    __syncthreads();
    for (int idx = tid; idx < 128 * 32; idx += 256) {
      int d = idx & 31, row = idx >> 5;
      int gi = ib + row;
      int gj = jb + row;
      sA[d][row] = (gi < NB1) ? mu[((size_t)s * N_ + gi) * 32 + d] : 0.f;
      sB[d][row] = (gj < NB1) ? mu[((size_t)s * N_ + NB1 + gj) * 32 + d] : 0.f;
    }
    __syncthreads();
    float acc[8][8];
#pragma unroll
    for (int i = 0; i < 8; ++i)
#pragma unroll
      for (int j = 0; j < 8; ++j) acc[i][j] = 0.f;
#pragma unroll 4
    for (int k = 0; k < 32; ++k) {
      float a[8], b[8];
      *(float4*)&a[0] = *(const float4*)&sA[k][ty * 8];
      *(float4*)&a[4] = *(const float4*)&sA[k][ty * 8 + 4];
      *(float4*)&b[0] = *(const float4*)&sB[k][tx * 8];
      *(float4*)&b[4] = *(const float4*)&sB[k][tx * 8 + 4];
#pragma unroll
      for (int i = 0; i < 8; ++i)
#pragma unroll
        for (int j = 0; j < 8; ++j) acc[i][j] = fmaf(a[i], b[j], acc[i][j]);
    }
#pragma unroll
    for (int i = 0; i < 8; ++i)
#pragma unroll
      for (int j = 0; j < 8; ++j) res[i][j] += sigmoidf_(acc[i][j]);
  }

  const bool fullc = (jb + 128) <= NB1;
#pragma unroll
  for (int i = 0; i < 8; ++i) {
    int row = ib + ty * 8 + i;
    if (row < NB1) {
      if (fullc) {
        float4 p0, p1;
        p0.x = 0.5f * res[i][0]; p0.y = 0.5f * res[i][1];
        p0.z = 0.5f * res[i][2]; p0.w = 0.5f * res[i][3];
        p1.x = 0.5f * res[i][4]; p1.y = 0.5f * res[i][5];
        p1.z = 0.5f * res[i][6]; p1.w = 0.5f * res[i][7];
        *(float4*)&out[(size_t)row * NB1 + jb + tx * 8]     = p0;
        *(float4*)&out[(size_t)row * NB1 + jb + tx * 8 + 4] = p1;
      } else {
#pragma unroll
        for (int j = 0; j < 8; ++j) {
          int col = jb + tx * 8 + j;
          if (col < NB1) out[(size_t)row * NB1 + col] = 0.5f * res[i][j];
        }
      }
    }
  }
}

__global__ void rk2_kernel(const float* __restrict__ rk_lgt, float* __restrict__ out) {
  int i = threadIdx.x;
  if (i < 32) out[i] = sigmoidf_(rk_lgt[i]);
}

// ---------------- host ----------------
static inline size_t align256(size_t x) { return (x + 255) & ~(size_t)255; }

extern "C" void kernel_launch(void* const* d_in, const int* in_sizes, int n_in,
                              void* d_out, int out_size, void* d_ws, size_t ws_size,
                              hipStream_t stream) {
  (void)in_sizes; (void)n_in; (void)out_size; (void)d_ws; (void)ws_size;
  const float* x      = (const float*)d_in[0];
  const float* noise  = (const float*)d_in[1];
  const float* W1     = (const float*)d_in[2];
  const float* al1    = (const float*)d_in[3];
  const float* ar1    = (const float*)d_in[4];
  const float* We     = (const float*)d_in[5];
  const float* ale    = (const float*)d_in[6];
  const float* are    = (const float*)d_in[7];
  const float* W2     = (const float*)d_in[8];
  const float* al2    = (const float*)d_in[9];
  const float* ar2    = (const float*)d_in[10];
  const float* W3     = (const float*)d_in[11];
  const float* al3    = (const float*)d_in[12];
  const float* ar3    = (const float*)d_in[13];
  const float* rk_lgt = (const float*)d_in[14];
  const int*   src    = (const int*)d_in[15];
  const int*   dst    = (const int*)d_in[16];

  float* out_adj    = (float*)d_out;                       // (1,6000,6000)
  float* out_mu     = out_adj + (size_t)NB1 * NB1;         // (2,20000,32) @ 36,000,000
  float* out_logvar = out_mu + (size_t)2 * N_ * 32;        // (20000,32)   @ 37,280,000
  float* out_rk2    = out_logvar + (size_t)N_ * 32;        // (1,32)       @ 37,920,000

  // Scratch in the f32 adj region (144 MB; we use 81.4 MB), dead before adj.
  char* sc = (char*)d_out;
  size_t off = 0;
  int*   ptr     = (int*)(sc + off);   off += align256((size_t)R_ * (N_ + 1) * 4);  //    240,128
  int*   csr_src = (int*)(sc + off);   off += align256((size_t)R_ * E_ * 4);        //  2,400,256
  float* el      = (float*)(sc + off); off += align256((size_t)R_ * N_ * 4 * 4);    //    960,000
  float* er      = (float*)(sc + off); off += align256((size_t)R_ * N_ * 4 * 4);    //    960,000
  float* hx      = (float*)(sc + off); off += align256((size_t)N_ * 64 * 4);        //  5,120,000
  float* h1      = (float*)(sc + off); off += align256((size_t)2 * N_ * 64 * 4);    // 10,240,000
  float* h       = (float*)(sc + off); off += align256((size_t)R_ * N_ * 256 * 4);  // 61,440,000
  // total 81,360,384 B < 144,000,000 B (f32 adj region)
  // counts/fill alias the h region (dead after CSR build; h written later)
  int* counts = (int*)(void*)h;
  int* fill   = (int*)(void*)((char*)(void*)h + align256((size_t)R_ * N_ * 4));

  // ---- CSR (dst shared by all 6 rgat calls) ----
  hipMemsetAsync(counts, 0, (size_t)R_ * N_ * 4, stream);
  hipMemsetAsync(fill, 0, (size_t)R_ * N_ * 4, stream);
  int eblocks = (R_ * E_ + 255) / 256;
  hist_kernel<<<eblocks, 256, 0, stream>>>(dst, counts);
  scan_kernel<<<R_, 1024, 0, stream>>>(counts, ptr);
  scatter_kernel<<<eblocks, 256, 0, stream>>>(src, dst, ptr, fill, csr_src);

  const dim3 g256((N_ + 63) / 64, 4, R_);
  const dim3 g64((N_ + 63) / 64, 1, R_);

  // hiddenx = rgat(x, W1, al1, ar1, relu) -> hx (f32)
  gemm_el_kernel<128, 256, 4, 64><<<g256, 256, 0, stream>>>(x, W1, al1, ar1, h, el, er);
  agg_kernel<4, 64, true><<<N_, 256, 0, stream>>>(h, el, er, ptr, csr_src, nullptr, hx);

  // hidden1[s] = hiddenx + rgat(noise[s], We, ale, are, relu) -> h1 (f32)
  for (int s = 0; s < 2; ++s) {
    gemm_el_kernel<64, 256, 4, 64><<<g256, 256, 0, stream>>>(
        noise + (size_t)s * N_ * 64, We, ale, are, h, el, er);
    agg_kernel<4, 64, true><<<N_, 256, 0, stream>>>(
        h, el, er, ptr, csr_src, hx, h1 + (size_t)s * N_ * 64);
  }

  // mu[s] = rgat(hidden1[s], W2, al2, ar2, ident) -> out_mu (f32, real output)
  for (int s = 0; s < 2; ++s) {
    gemm_el_kernel<64, 64, 2, 32><<<g64, 256, 0, stream>>>(
        h1 + (size_t)s * N_ * 64, W2, al2, ar2, h, el, er);
    agg_kernel<2, 32, false><<<N_, 128, 0, stream>>>(
        h, el, er, ptr, csr_src, nullptr, out_mu + (size_t)s * N_ * 32);
  }

  // logvar = rgat(hiddenx, W3, al3, ar3, ident) -> out_logvar (f32)
  gemm_el_kernel<64, 64, 2, 32><<<g64, 256, 0, stream>>>(hx, W3, al3, ar3, h, el, er);
  agg_kernel<2, 32, false><<<N_, 128, 0, stream>>>(
      h, el, er, ptr, csr_src, nullptr, out_logvar);

  rk2_kernel<<<1, 32, 0, stream>>>(rk_lgt, out_rk2);

  // adj: reads out_mu (disjoint range), overwrites the adj-region scratch.
  adj_kernel<<<dim3((NB1 + 127) / 128, (NB1 + 127) / 128), 256, 0, stream>>>(out_mu, out_adj);
}

// Round 2
// 1026.632 us; speedup vs baseline: 1.4332x; 1.0280x over previous
//
#include <hip/hip_runtime.h>
#include <hip/hip_bf16.h>

// RGAT pipeline for MI355X. Inputs f32, OUTPUTS f32. Scratch (81.4 MB) lives
// in d_out's f32 adj region (144 MB), all dead before adj_kernel, which reads
// mu from out_mu (disjoint from the adj range it writes). d_ws/d_in untouched.
//
// R1: agg_kernel flash-style online-softmax (1x gather+exp per edge),
//     vectorized multi-edge float4 gather via register shuffles.
// R2: adj_kernel restructured: 512 threads, 128x128 tile, 8x4 per-thread
//     blocking (res+acc = 64 live floats, no spills; prior 8x8 had 128 live
//     floats vs VGPR_Count=84 -> scratch spills). Conflict-free LDS staging
//     (transposed scalar writes, consecutive lanes -> consecutive banks) and
//     conflict-free fragment reads (contiguous float4 per wave; prior tx*8
//     stride was a 4-way read conflict, 7.9M conflict cycles).

static constexpr int N_  = 20000;
static constexpr int R_  = 3;
static constexpr int E_  = 200000;
static constexpr int NB1 = 6000;   // N1 == N2 == 6000

__device__ __forceinline__ float sigmoidf_(float x) {
  return 1.0f / (1.0f + __expf(-x));
}

// ---------------- CSR build ----------------
__global__ void hist_kernel(const int* __restrict__ dst, int* __restrict__ counts) {
  int i = blockIdx.x * blockDim.x + threadIdx.x;
  if (i >= R_ * E_) return;
  int r = i / E_;
  atomicAdd(&counts[r * N_ + dst[i]], 1);
}

__global__ void scan_kernel(const int* __restrict__ counts, int* __restrict__ ptr) {
  int r = blockIdx.x;
  __shared__ int buf[1024];
  __shared__ int carry;
  int tid = threadIdx.x;
  if (tid == 0) carry = 0;
  __syncthreads();
  for (int base = 0; base < N_; base += 1024) {
    int i = base + tid;
    int v = (i < N_) ? counts[r * N_ + i] : 0;
    buf[tid] = v;
    __syncthreads();
    for (int off = 1; off < 1024; off <<= 1) {
      int t = (tid >= off) ? buf[tid - off] : 0;
      __syncthreads();
      buf[tid] += t;
      __syncthreads();
    }
    int c = carry;
    if (i < N_) ptr[r * (N_ + 1) + i] = c + buf[tid] - v;  // exclusive scan
    __syncthreads();
    if (tid == 1023) carry = c + buf[1023];
    __syncthreads();
  }
  if (tid == 0) ptr[r * (N_ + 1) + N_] = carry;
}

__global__ void scatter_kernel(const int* __restrict__ src, const int* __restrict__ dst,
                               const int* __restrict__ ptr, int* __restrict__ fill,
                               int* __restrict__ csrc) {
  int i = blockIdx.x * blockDim.x + threadIdx.x;
  if (i >= R_ * E_) return;
  int r = i / E_;
  int d = dst[i];
  int pos = ptr[r * (N_ + 1) + d] + atomicAdd(&fill[r * N_ + d], 1);
  csrc[r * E_ + pos] = src[i];
}

// ---------------- GEMM + fused attention-logit epilogue ----------------
// h[r][n][HF] = A[n][:] @ W[r][:][:] (f32); el/er[r][n][hh] = sum_f h*al/ar.
// 256 threads = 16x16, tile 64 nodes x 64 cols, 4x4 register blocking.
template <int DIN, int HF, int H, int F>
__global__ __launch_bounds__(256) void gemm_el_kernel(
    const float* __restrict__ A, const float* __restrict__ W,
    const float* __restrict__ al, const float* __restrict__ ar,
    float* __restrict__ h, float* __restrict__ el, float* __restrict__ er) {
  __shared__ float sAT[64][68];  // [k][node]
  __shared__ float sW[64][68];   // [k][col]
  const int nb  = blockIdx.x * 64;
  const int cg  = blockIdx.y;    // 64-col group
  const int r   = blockIdx.z;
  const int tid = threadIdx.x;
  const int ty  = tid >> 4, tx = tid & 15;

  float acc[4][4];
#pragma unroll
  for (int i = 0; i < 4; ++i)
#pragma unroll
    for (int j = 0; j < 4; ++j) acc[i][j] = 0.f;

  for (int k0 = 0; k0 < DIN; k0 += 64) {
    for (int idx = tid; idx < 4096; idx += 256) {
      int nl = idx >> 6, kk = idx & 63;
      int n = nb + nl;
      sAT[kk][nl] = (n < N_) ? A[(size_t)n * DIN + k0 + kk] : 0.f;
    }
    for (int idx = tid; idx < 4096; idx += 256) {
      int kk = idx >> 6, cl = idx & 63;
      sW[kk][cl] = W[((size_t)r * DIN + k0 + kk) * HF + cg * 64 + cl];
    }
    __syncthreads();
#pragma unroll 8
    for (int kk = 0; kk < 64; ++kk) {
      const float4 a4 = *(const float4*)&sAT[kk][ty * 4];
      const float4 w4 = *(const float4*)&sW[kk][tx * 4];
      const float a[4] = {a4.x, a4.y, a4.z, a4.w};
      const float w[4] = {w4.x, w4.y, w4.z, w4.w};
#pragma unroll
      for (int i = 0; i < 4; ++i)
#pragma unroll
        for (int j = 0; j < 4; ++j) acc[i][j] = fmaf(a[i], w[j], acc[i][j]);
    }
    __syncthreads();
  }

  // store h (float4 per row)
  const int c0 = cg * 64 + tx * 4;
#pragma unroll
  for (int i = 0; i < 4; ++i) {
    int n = nb + ty * 4 + i;
    if (n < N_) {
      float4 v; v.x = acc[i][0]; v.y = acc[i][1]; v.z = acc[i][2]; v.w = acc[i][3];
      *(float4*)&h[((size_t)r * N_ + n) * HF + c0] = v;
    }
  }

  // fused el/er: reduce over f within head via shuffles (group width G = F/4)
  const int hh = c0 / F;
  const int f0 = c0 % F;
  float al4[4], ar4[4];
#pragma unroll
  for (int j = 0; j < 4; ++j) {
    al4[j] = al[((size_t)r * H + hh) * F + f0 + j];
    ar4[j] = ar[((size_t)r * H + hh) * F + f0 + j];
  }
  float elp[4], erp[4];
#pragma unroll
  for (int i = 0; i < 4; ++i) {
    elp[i] = acc[i][0] * al4[0] + acc[i][1] * al4[1] + acc[i][2] * al4[2] + acc[i][3] * al4[3];
    erp[i] = acc[i][0] * ar4[0] + acc[i][1] * ar4[1] + acc[i][2] * ar4[2] + acc[i][3] * ar4[3];
  }
  constexpr int G = F / 4;  // tx-threads per head: 16 (F=64) or 8 (F=32)
#pragma unroll
  for (int off = G / 2; off >= 1; off >>= 1) {
#pragma unroll
    for (int i = 0; i < 4; ++i) {
      elp[i] += __shfl_down(elp[i], off, G);
      erp[i] += __shfl_down(erp[i], off, G);
    }
  }
  if ((tx & (G - 1)) == 0) {
#pragma unroll
    for (int i = 0; i < 4; ++i) {
      int n = nb + ty * 4 + i;
      if (n < N_) {
        el[((size_t)r * N_ + n) * H + hh] = elp[i];
        er[((size_t)r * N_ + n) * H + hh] = erp[i];
      }
    }
  }
}

// ---------------- Per-destination edge softmax + aggregation ----------------
// One block per node; wave = head. Flash-style online softmax per 64-edge
// chunk: lane-parallel logits (one el gather + one exp per edge), then a
// vectorized gather phase processing EPG edges per iteration with float4
// h-row loads; (src, w) broadcast via register shuffles. Accumulate over R
// relations (f32), then head-mean + activation + optional base add.
template <int H, int F, bool RELU>
__global__ __launch_bounds__(256) void agg_kernel(
    const float* __restrict__ h, const float* __restrict__ el, const float* __restrict__ er,
    const int* __restrict__ ptr, const int* __restrict__ srcs,
    const float* __restrict__ base, float* __restrict__ outf) {
  constexpr int VL  = F / 4;    // lanes per edge-row (float4 granules): 16 or 8
  constexpr int EPG = 64 / VL;  // edges per wave-iteration: 4 or 8
  const int n    = blockIdx.x;
  const int wave = threadIdx.x >> 6;   // = head
  const int lane = threadIdx.x & 63;
  const int eg   = lane / VL;          // edge slot within iteration
  const int fl   = lane % VL;          // float4 index within row

  float4 tot = {0.f, 0.f, 0.f, 0.f};

  for (int r = 0; r < R_; ++r) {
    const int p0  = ptr[r * (N_ + 1) + n];
    const int deg = ptr[r * (N_ + 1) + n + 1] - p0;
    if (deg == 0) continue;
    const int* sp = srcs + (size_t)r * E_ + p0;
    const float erv = er[((size_t)r * N_ + n) * H + wave];

    float m = -3.0e38f, dsum = 0.f;
    float4 racc = {0.f, 0.f, 0.f, 0.f};

    for (int b0 = 0; b0 < deg; b0 += 64) {
      const int cnt = min(64, deg - b0);
      int   s = 0;
      float e = -3.0e38f;
      if (lane < cnt) {
        s = sp[b0 + lane];
        e = el[((size_t)r * N_ + s) * H + wave] + erv;
        e = (e > 0.f) ? e : 0.2f * e;
      }
      // chunk max (butterfly; all lanes end with the max)
      float mloc = e;
#pragma unroll
      for (int off = 32; off >= 1; off >>= 1)
        mloc = fmaxf(mloc, __shfl_xor(mloc, off, 64));
      const float mnew  = fmaxf(m, mloc);
      const float scale = __expf(m - mnew);   // 0 on first chunk (m = -3e38)
      const float w = __expf(e - mnew);       // exactly 0 for padded lanes
      float wsum = w;
#pragma unroll
      for (int off = 32; off >= 1; off >>= 1)
        wsum += __shfl_xor(wsum, off, 64);
      dsum = fmaf(dsum, scale, wsum);
      racc.x *= scale; racc.y *= scale; racc.z *= scale; racc.w *= scale;
      m = mnew;

      // gather: uniform trip count; padded slots have w=0, s=0 (safe load)
      const int kmax = (cnt + EPG - 1) / EPG;
      for (int k = 0; k < kmax; ++k) {
        const int i2 = eg + k * EPG;          // < 64 always
        const int   s2 = __shfl(s, i2, 64);
        const float w2 = __shfl(w, i2, 64);
        const float4 hv =
            *(const float4*)&h[((size_t)r * N_ + s2) * (H * F) + wave * F + fl * 4];
        racc.x = fmaf(w2, hv.x, racc.x);
        racc.y = fmaf(w2, hv.y, racc.y);
        racc.z = fmaf(w2, hv.z, racc.z);
        racc.w = fmaf(w2, hv.w, racc.w);
      }
    }
    const float inv = 1.0f / (dsum + 1e-16f);
    tot.x = fmaf(racc.x, inv, tot.x);
    tot.y = fmaf(racc.y, inv, tot.y);
    tot.z = fmaf(racc.z, inv, tot.z);
    tot.w = fmaf(racc.w, inv, tot.w);
  }

  // reduce across edge-groups (xor butterfly over offsets VL..32)
#pragma unroll
  for (int off = VL; off < 64; off <<= 1) {
    tot.x += __shfl_xor(tot.x, off, 64);
    tot.y += __shfl_xor(tot.y, off, 64);
    tot.z += __shfl_xor(tot.z, off, 64);
    tot.w += __shfl_xor(tot.w, off, 64);
  }

  __shared__ float4 sh4[H][VL];
  if (eg == 0) sh4[wave][fl] = tot;
  __syncthreads();
  if (threadIdx.x < VL) {
    float4 v = sh4[0][threadIdx.x];
#pragma unroll
    for (int hh = 1; hh < H; ++hh) {
      float4 u = sh4[hh][threadIdx.x];
      v.x += u.x; v.y += u.y; v.z += u.z; v.w += u.w;
    }
    const float sc = 1.0f / H;
    v.x *= sc; v.y *= sc; v.z *= sc; v.w *= sc;
    if (RELU) {
      v.x = fmaxf(v.x, 0.f); v.y = fmaxf(v.y, 0.f);
      v.z = fmaxf(v.z, 0.f); v.w = fmaxf(v.w, 0.f);
    }
    if (base) {
      float4 bv = *(const float4*)&base[(size_t)n * F + threadIdx.x * 4];
      v.x += bv.x; v.y += bv.y; v.z += bv.z; v.w += bv.w;
    }
    *(float4*)&outf[(size_t)n * F + threadIdx.x * 4] = v;
  }
}

// ---------------- adj = mean_s sigmoid(z1[s] @ z2[s]^T) ----------------
// Reads f32 mu from out_mu (d_out elements [36M,37.28M)) and writes only the
// adj range [0,36M) -- disjoint, no hazard.
// 512 threads, tile 128x128, 8 rows x 4 cols per thread (64 live accumulator
// floats -> no spills). Staging: float4 global load, transposed scalar LDS
// writes (consecutive lanes -> consecutive rows -> consecutive banks, free).
// Fragment reads: B = one float4 at sB[k][tx*4] (contiguous per wave, free);
// A = quad-split broadcasts sA[k][ty*4] and sA[k][64+ty*4].
__global__ __launch_bounds__(512) void adj_kernel(const float* __restrict__ mu,
                                                  float* __restrict__ out) {
  __shared__ float sA[32][128];  // [d][i_local]
  __shared__ float sB[32][128];  // [d][j_local]
  const int jb = blockIdx.x * 128;
  const int ib = blockIdx.y * 128;
  const int tid = threadIdx.x;
  const int ty = tid >> 5;   // 0..15: row group (quad-split: ty*4 and 64+ty*4)
  const int tx = tid & 31;   // 0..31: col quad (tx*4)

  float res[8][4];
#pragma unroll
  for (int i = 0; i < 8; ++i)
#pragma unroll
    for (int j = 0; j < 4; ++j) res[i][j] = 0.f;

  for (int s = 0; s < 2; ++s) {
    __syncthreads();
#pragma unroll
    for (int it = 0; it < 2; ++it) {
      int idx = tid + it * 512;
      int dg = idx >> 7, row = idx & 127;   // dg: 0..7 (float4 group of d)
      int gi = ib + row;
      int gj = jb + row;
      float4 va = {0.f, 0.f, 0.f, 0.f}, vb = {0.f, 0.f, 0.f, 0.f};
      if (gi < NB1) va = *(const float4*)&mu[((size_t)s * N_ + gi) * 32 + dg * 4];
      if (gj < NB1) vb = *(const float4*)&mu[((size_t)s * N_ + NB1 + gj) * 32 + dg * 4];
      sA[dg * 4 + 0][row] = va.x; sA[dg * 4 + 1][row] = va.y;
      sA[dg * 4 + 2][row] = va.z; sA[dg * 4 + 3][row] = va.w;
      sB[dg * 4 + 0][row] = vb.x; sB[dg * 4 + 1][row] = vb.y;
      sB[dg * 4 + 2][row] = vb.z; sB[dg * 4 + 3][row] = vb.w;
    }
    __syncthreads();

    float acc[8][4];
#pragma unroll
    for (int i = 0; i < 8; ++i)
#pragma unroll
      for (int j = 0; j < 4; ++j) acc[i][j] = 0.f;
#pragma unroll 8
    for (int k = 0; k < 32; ++k) {
      float a[8], b[4];
      *(float4*)&a[0] = *(const float4*)&sA[k][ty * 4];
      *(float4*)&a[4] = *(const float4*)&sA[k][64 + ty * 4];
      *(float4*)&b[0] = *(const float4*)&sB[k][tx * 4];
#pragma unroll
      for (int i = 0; i < 8; ++i)
#pragma unroll
        for (int j = 0; j < 4; ++j) acc[i][j] = fmaf(a[i], b[j], acc[i][j]);
    }
#pragma unroll
    for (int i = 0; i < 8; ++i)
#pragma unroll
      for (int j = 0; j < 4; ++j) res[i][j] += sigmoidf_(acc[i][j]);
  }

  const bool fullc = (jb + 128) <= NB1;
#pragma unroll
  for (int i = 0; i < 8; ++i) {
    int row = ib + ((i < 4) ? (ty * 4 + i) : (64 + ty * 4 + (i - 4)));
    if (row < NB1) {
      int col = jb + tx * 4;
      if (fullc) {
        float4 p;
        p.x = 0.5f * res[i][0]; p.y = 0.5f * res[i][1];
        p.z = 0.5f * res[i][2]; p.w = 0.5f * res[i][3];
        *(float4*)&out[(size_t)row * NB1 + col] = p;
      } else {
#pragma unroll
        for (int j = 0; j < 4; ++j) {
          if (col + j < NB1) out[(size_t)row * NB1 + col + j] = 0.5f * res[i][j];
        }
      }
    }
  }
}

__global__ void rk2_kernel(const float* __restrict__ rk_lgt, float* __restrict__ out) {
  int i = threadIdx.x;
  if (i < 32) out[i] = sigmoidf_(rk_lgt[i]);
}

// ---------------- host ----------------
static inline size_t align256(size_t x) { return (x + 255) & ~(size_t)255; }

extern "C" void kernel_launch(void* const* d_in, const int* in_sizes, int n_in,
                              void* d_out, int out_size, void* d_ws, size_t ws_size,
                              hipStream_t stream) {
  (void)in_sizes; (void)n_in; (void)out_size; (void)d_ws; (void)ws_size;
  const float* x      = (const float*)d_in[0];
  const float* noise  = (const float*)d_in[1];
  const float* W1     = (const float*)d_in[2];
  const float* al1    = (const float*)d_in[3];
  const float* ar1    = (const float*)d_in[4];
  const float* We     = (const float*)d_in[5];
  const float* ale    = (const float*)d_in[6];
  const float* are    = (const float*)d_in[7];
  const float* W2     = (const float*)d_in[8];
  const float* al2    = (const float*)d_in[9];
  const float* ar2    = (const float*)d_in[10];
  const float* W3     = (const float*)d_in[11];
  const float* al3    = (const float*)d_in[12];
  const float* ar3    = (const float*)d_in[13];
  const float* rk_lgt = (const float*)d_in[14];
  const int*   src    = (const int*)d_in[15];
  const int*   dst    = (const int*)d_in[16];

  float* out_adj    = (float*)d_out;                       // (1,6000,6000)
  float* out_mu     = out_adj + (size_t)NB1 * NB1;         // (2,20000,32) @ 36,000,000
  float* out_logvar = out_mu + (size_t)2 * N_ * 32;        // (20000,32)   @ 37,280,000
  float* out_rk2    = out_logvar + (size_t)N_ * 32;        // (1,32)       @ 37,920,000

  // Scratch in the f32 adj region (144 MB; we use 81.4 MB), dead before adj.
  char* sc = (char*)d_out;
  size_t off = 0;
  int*   ptr     = (int*)(sc + off);   off += align256((size_t)R_ * (N_ + 1) * 4);  //    240,128
  int*   csr_src = (int*)(sc + off);   off += align256((size_t)R_ * E_ * 4);        //  2,400,256
  float* el      = (float*)(sc + off); off += align256((size_t)R_ * N_ * 4 * 4);    //    960,000
  float* er      = (float*)(sc + off); off += align256((size_t)R_ * N_ * 4 * 4);    //    960,000
  float* hx      = (float*)(sc + off); off += align256((size_t)N_ * 64 * 4);        //  5,120,000
  float* h1      = (float*)(sc + off); off += align256((size_t)2 * N_ * 64 * 4);    // 10,240,000
  float* h       = (float*)(sc + off); off += align256((size_t)R_ * N_ * 256 * 4);  // 61,440,000
  // total 81,360,384 B < 144,000,000 B (f32 adj region)
  // counts/fill alias the h region (dead after CSR build; h written later)
  int* counts = (int*)(void*)h;
  int* fill   = (int*)(void*)((char*)(void*)h + align256((size_t)R_ * N_ * 4));

  // ---- CSR (dst shared by all 6 rgat calls) ----
  hipMemsetAsync(counts, 0, (size_t)R_ * N_ * 4, stream);
  hipMemsetAsync(fill, 0, (size_t)R_ * N_ * 4, stream);
  int eblocks = (R_ * E_ + 255) / 256;
  hist_kernel<<<eblocks, 256, 0, stream>>>(dst, counts);
  scan_kernel<<<R_, 1024, 0, stream>>>(counts, ptr);
  scatter_kernel<<<eblocks, 256, 0, stream>>>(src, dst, ptr, fill, csr_src);

  const dim3 g256((N_ + 63) / 64, 4, R_);
  const dim3 g64((N_ + 63) / 64, 1, R_);

  // hiddenx = rgat(x, W1, al1, ar1, relu) -> hx (f32)
  gemm_el_kernel<128, 256, 4, 64><<<g256, 256, 0, stream>>>(x, W1, al1, ar1, h, el, er);
  agg_kernel<4, 64, true><<<N_, 256, 0, stream>>>(h, el, er, ptr, csr_src, nullptr, hx);

  // hidden1[s] = hiddenx + rgat(noise[s], We, ale, are, relu) -> h1 (f32)
  for (int s = 0; s < 2; ++s) {
    gemm_el_kernel<64, 256, 4, 64><<<g256, 256, 0, stream>>>(
        noise + (size_t)s * N_ * 64, We, ale, are, h, el, er);
    agg_kernel<4, 64, true><<<N_, 256, 0, stream>>>(
        h, el, er, ptr, csr_src, hx, h1 + (size_t)s * N_ * 64);
  }

  // mu[s] = rgat(hidden1[s], W2, al2, ar2, ident) -> out_mu (f32, real output)
  for (int s = 0; s < 2; ++s) {
    gemm_el_kernel<64, 64, 2, 32><<<g64, 256, 0, stream>>>(
        h1 + (size_t)s * N_ * 64, W2, al2, ar2, h, el, er);
    agg_kernel<2, 32, false><<<N_, 128, 0, stream>>>(
        h, el, er, ptr, csr_src, nullptr, out_mu + (size_t)s * N_ * 32);
  }

  // logvar = rgat(hiddenx, W3, al3, ar3, ident) -> out_logvar (f32)
  gemm_el_kernel<64, 64, 2, 32><<<g64, 256, 0, stream>>>(hx, W3, al3, ar3, h, el, er);
  agg_kernel<2, 32, false><<<N_, 128, 0, stream>>>(
      h, el, er, ptr, csr_src, nullptr, out_logvar);

  rk2_kernel<<<1, 32, 0, stream>>>(rk_lgt, out_rk2);

  // adj: reads out_mu (disjoint range), overwrites the adj-region scratch.
  adj_kernel<<<dim3((NB1 + 127) / 128, (NB1 + 127) / 128), 512, 0, stream>>>(out_mu, out_adj);
}

// Round 5
// 971.128 us; speedup vs baseline: 1.5151x; 1.0572x over previous
//
#include <hip/hip_runtime.h>
#include <hip/hip_bf16.h>

// RGAT pipeline for MI355X. Inputs f32, OUTPUTS f32. Scratch (~84.2 MB) lives
// in d_out's f32 adj region (144 MB), all dead before adj_kernel, which reads
// mu from out_mu (disjoint from the adj range it writes). d_ws/d_in untouched.
//
// R1: agg flash-style online-softmax, vectorized multi-edge float4 gather.
// R2: adj 512-thr 8x4 blocking, conflict-free LDS.
// R3/R4 FAILED: el3/er3 aliased onto el/er but need 1.44 MB each vs the
//     960 KB el/er regions -> el3[inst2] (logvar el) collided with
//     er3[inst0] (mu s0 er), deterministically corrupting mu (identical
//     absmax 2.54e-2 in both rounds). NOT a numerics issue.
// R5: dedicated el3/er3 allocations (1.44 MB each). Agg keeps R2-verified
//     numerics; 3-phase CSR scan and batched mu/mu/logvar layers kept.

static constexpr int N_  = 20000;
static constexpr int R_  = 3;
static constexpr int E_  = 200000;
static constexpr int NB1 = 6000;   // N1 == N2 == 6000

__device__ __forceinline__ float sigmoidf_(float x) {
  return 1.0f / (1.0f + __expf(-x));
}

// ---------------- CSR build ----------------
__global__ void hist_kernel(const int* __restrict__ dst, int* __restrict__ counts) {
  int i = blockIdx.x * blockDim.x + threadIdx.x;
  if (i >= R_ * E_) return;
  int r = i / E_;
  atomicAdd(&counts[r * N_ + dst[i]], 1);
}

static constexpr int SCAN_CH = 1024;
static constexpr int NCH = (N_ + SCAN_CH - 1) / SCAN_CH;  // 20

// Phase A: per-1024-chunk local exclusive scan + chunk totals.
__global__ __launch_bounds__(1024) void scan_partial_kernel(
    const int* __restrict__ counts, int* __restrict__ ptr, int* __restrict__ csums) {
  const int r = blockIdx.y, c = blockIdx.x, tid = threadIdx.x;
  __shared__ int buf[SCAN_CH];
  const int i = c * SCAN_CH + tid;
  const int v = (i < N_) ? counts[r * N_ + i] : 0;
  buf[tid] = v;
  __syncthreads();
  for (int off = 1; off < SCAN_CH; off <<= 1) {
    int t = (tid >= off) ? buf[tid - off] : 0;
    __syncthreads();
    buf[tid] += t;
    __syncthreads();
  }
  if (i < N_) ptr[r * (N_ + 1) + i] = buf[tid] - v;  // local exclusive
  if (tid == SCAN_CH - 1) csums[r * NCH + c] = buf[tid];
}

// Phase B: tiny serial scan of chunk totals (R_ threads, 20 entries each).
__global__ void scan_sums_kernel(int* __restrict__ csums, int* __restrict__ ptr) {
  int r = threadIdx.x;
  if (r < R_) {
    int acc = 0;
    for (int c = 0; c < NCH; ++c) {
      int t = csums[r * NCH + c];
      csums[r * NCH + c] = acc;
      acc += t;
    }
    ptr[r * (N_ + 1) + N_] = acc;
  }
}

// Phase C: add chunk bases.
__global__ __launch_bounds__(1024) void scan_add_kernel(
    const int* __restrict__ csums, int* __restrict__ ptr) {
  const int r = blockIdx.y, c = blockIdx.x, tid = threadIdx.x;
  const int i = c * SCAN_CH + tid;
  if (i < N_) ptr[r * (N_ + 1) + i] += csums[r * NCH + c];
}

__global__ void scatter_kernel(const int* __restrict__ src, const int* __restrict__ dst,
                               const int* __restrict__ ptr, int* __restrict__ fill,
                               int* __restrict__ csrc) {
  int i = blockIdx.x * blockDim.x + threadIdx.x;
  if (i >= R_ * E_) return;
  int r = i / E_;
  int d = dst[i];
  int pos = ptr[r * (N_ + 1) + d] + atomicAdd(&fill[r * N_ + d], 1);
  csrc[r * E_ + pos] = src[i];
}

// ---------------- GEMM + fused attention-logit epilogue ----------------
// h[r][n][HF] = A[n][:] @ W[r][:][:] (f32); el/er[r][n][hh] = sum_f h*al/ar.
// 256 threads = 16x16, tile 64 nodes x 64 cols, 4x4 register blocking.
template <int DIN, int HF, int H, int F>
__device__ __forceinline__ void gemm_el_dev(
    const int r, const float* __restrict__ A, const float* __restrict__ W,
    const float* __restrict__ al, const float* __restrict__ ar,
    float* __restrict__ h, float* __restrict__ el, float* __restrict__ er) {
  __shared__ float sAT[64][68];  // [k][node]
  __shared__ float sW[64][68];   // [k][col]
  const int nb  = blockIdx.x * 64;
  const int cg  = blockIdx.y;    // 64-col group
  const int tid = threadIdx.x;
  const int ty  = tid >> 4, tx = tid & 15;

  float acc[4][4];
#pragma unroll
  for (int i = 0; i < 4; ++i)
#pragma unroll
    for (int j = 0; j < 4; ++j) acc[i][j] = 0.f;

  for (int k0 = 0; k0 < DIN; k0 += 64) {
    for (int idx = tid; idx < 4096; idx += 256) {
      int nl = idx >> 6, kk = idx & 63;
      int n = nb + nl;
      sAT[kk][nl] = (n < N_) ? A[(size_t)n * DIN + k0 + kk] : 0.f;
    }
    for (int idx = tid; idx < 4096; idx += 256) {
      int kk = idx >> 6, cl = idx & 63;
      sW[kk][cl] = W[((size_t)r * DIN + k0 + kk) * HF + cg * 64 + cl];
    }
    __syncthreads();
#pragma unroll 8
    for (int kk = 0; kk < 64; ++kk) {
      const float4 a4 = *(const float4*)&sAT[kk][ty * 4];
      const float4 w4 = *(const float4*)&sW[kk][tx * 4];
      const float a[4] = {a4.x, a4.y, a4.z, a4.w};
      const float w[4] = {w4.x, w4.y, w4.z, w4.w};
#pragma unroll
      for (int i = 0; i < 4; ++i)
#pragma unroll
        for (int j = 0; j < 4; ++j) acc[i][j] = fmaf(a[i], w[j], acc[i][j]);
    }
    __syncthreads();
  }

  // store h (float4 per row)
  const int c0 = cg * 64 + tx * 4;
#pragma unroll
  for (int i = 0; i < 4; ++i) {
    int n = nb + ty * 4 + i;
    if (n < N_) {
      float4 v; v.x = acc[i][0]; v.y = acc[i][1]; v.z = acc[i][2]; v.w = acc[i][3];
      *(float4*)&h[((size_t)r * N_ + n) * HF + c0] = v;
    }
  }

  // fused el/er: reduce over f within head via shuffles (group width G = F/4)
  const int hh = c0 / F;
  const int f0 = c0 % F;
  float al4[4], ar4[4];
#pragma unroll
  for (int j = 0; j < 4; ++j) {
    al4[j] = al[((size_t)r * H + hh) * F + f0 + j];
    ar4[j] = ar[((size_t)r * H + hh) * F + f0 + j];
  }
  float elp[4], erp[4];
#pragma unroll
  for (int i = 0; i < 4; ++i) {
    elp[i] = acc[i][0] * al4[0] + acc[i][1] * al4[1] + acc[i][2] * al4[2] + acc[i][3] * al4[3];
    erp[i] = acc[i][0] * ar4[0] + acc[i][1] * ar4[1] + acc[i][2] * ar4[2] + acc[i][3] * ar4[3];
  }
  constexpr int G = F / 4;  // tx-threads per head: 16 (F=64) or 8 (F=32)
#pragma unroll
  for (int off = G / 2; off >= 1; off >>= 1) {
#pragma unroll
    for (int i = 0; i < 4; ++i) {
      elp[i] += __shfl_down(elp[i], off, G);
      erp[i] += __shfl_down(erp[i], off, G);
    }
  }
  if ((tx & (G - 1)) == 0) {
#pragma unroll
    for (int i = 0; i < 4; ++i) {
      int n = nb + ty * 4 + i;
      if (n < N_) {
        el[((size_t)r * N_ + n) * H + hh] = elp[i];
        er[((size_t)r * N_ + n) * H + hh] = erp[i];
      }
    }
  }
}

template <int DIN, int HF, int H, int F>
__global__ __launch_bounds__(256) void gemm_el_kernel(
    const float* __restrict__ A, const float* __restrict__ W,
    const float* __restrict__ al, const float* __restrict__ ar,
    float* __restrict__ h, float* __restrict__ el, float* __restrict__ er) {
  gemm_el_dev<DIN, HF, H, F>(blockIdx.z, A, W, al, ar, h, el, er);
}

// Batched variant: 3 instances (mu s0, mu s1, logvar), grid.z = 3*R_.
struct GemmB3 {
  const float* A[3]; const float* W[3]; const float* al[3]; const float* ar[3];
  float* h[3]; float* el[3]; float* er[3];
};
template <int DIN, int HF, int H, int F>
__global__ __launch_bounds__(256) void gemm_el_b3_kernel(GemmB3 a) {
  const int inst = blockIdx.z / R_;
  const int r    = blockIdx.z % R_;
  gemm_el_dev<DIN, HF, H, F>(r, a.A[inst], a.W[inst], a.al[inst], a.ar[inst],
                             a.h[inst], a.el[inst], a.er[inst]);
}

// ---------------- Per-destination edge softmax + aggregation ----------------
// One block per node; wave = head. Flash-style online softmax per 64-edge
// chunk (R2-verified numerics: chunk max butterfly + chunk wsum butterfly +
// online rescale), then a vectorized gather phase processing EPG edges per
// iteration with float4 h-row loads; (src, w) broadcast via register
// shuffles. Accumulate over R relations (f32), then head-mean + activation +
// optional base add.
template <int H, int F, bool RELU>
__device__ __forceinline__ void agg_dev(
    const int n, const float* __restrict__ h, const float* __restrict__ el,
    const float* __restrict__ er, const int* __restrict__ ptr,
    const int* __restrict__ srcs, const float* __restrict__ base,
    float* __restrict__ outf) {
  constexpr int VL  = F / 4;    // lanes per edge-row (float4 granules): 16 or 8
  constexpr int EPG = 64 / VL;  // edges per wave-iteration: 4 or 8
  const int wave = threadIdx.x >> 6;   // = head
  const int lane = threadIdx.x & 63;
  const int eg   = lane / VL;          // edge slot within iteration
  const int fl   = lane % VL;          // float4 index within row

  float4 tot = {0.f, 0.f, 0.f, 0.f};

  for (int r = 0; r < R_; ++r) {
    const int p0  = ptr[r * (N_ + 1) + n];
    const int deg = ptr[r * (N_ + 1) + n + 1] - p0;
    if (deg == 0) continue;
    const int* sp = srcs + (size_t)r * E_ + p0;
    const float erv = er[((size_t)r * N_ + n) * H + wave];

    float m = -3.0e38f, dsum = 0.f;
    float4 racc = {0.f, 0.f, 0.f, 0.f};

    for (int b0 = 0; b0 < deg; b0 += 64) {
      const int cnt = min(64, deg - b0);
      int   s = 0;
      float e = -3.0e38f;
      if (lane < cnt) {
        s = sp[b0 + lane];
        e = el[((size_t)r * N_ + s) * H + wave] + erv;
        e = (e > 0.f) ? e : 0.2f * e;
      }
      // chunk max (butterfly; all lanes end with the max)
      float mloc = e;
#pragma unroll
      for (int off = 32; off >= 1; off >>= 1)
        mloc = fmaxf(mloc, __shfl_xor(mloc, off, 64));
      const float mnew  = fmaxf(m, mloc);
      const float scale = __expf(m - mnew);   // 0 on first chunk (m = -3e38)
      const float w = __expf(e - mnew);       // exactly 0 for padded lanes
      float wsum = w;
#pragma unroll
      for (int off = 32; off >= 1; off >>= 1)
        wsum += __shfl_xor(wsum, off, 64);
      dsum = fmaf(dsum, scale, wsum);
      racc.x *= scale; racc.y *= scale; racc.z *= scale; racc.w *= scale;
      m = mnew;

      // gather: uniform trip count; padded slots have w=0, s=0 (safe load)
      const int kmax = (cnt + EPG - 1) / EPG;
      for (int k = 0; k < kmax; ++k) {
        const int i2 = eg + k * EPG;          // < 64 always
        const int   s2 = __shfl(s, i2, 64);
        const float w2 = __shfl(w, i2, 64);
        const float4 hv =
            *(const float4*)&h[((size_t)r * N_ + s2) * (H * F) + wave * F + fl * 4];
        racc.x = fmaf(w2, hv.x, racc.x);
        racc.y = fmaf(w2, hv.y, racc.y);
        racc.z = fmaf(w2, hv.z, racc.z);
        racc.w = fmaf(w2, hv.w, racc.w);
      }
    }
    const float inv = 1.0f / (dsum + 1e-16f);
    tot.x = fmaf(racc.x, inv, tot.x);
    tot.y = fmaf(racc.y, inv, tot.y);
    tot.z = fmaf(racc.z, inv, tot.z);
    tot.w = fmaf(racc.w, inv, tot.w);
  }

  // reduce across edge-groups (xor butterfly over offsets VL..32)
#pragma unroll
  for (int off = VL; off < 64; off <<= 1) {
    tot.x += __shfl_xor(tot.x, off, 64);
    tot.y += __shfl_xor(tot.y, off, 64);
    tot.z += __shfl_xor(tot.z, off, 64);
    tot.w += __shfl_xor(tot.w, off, 64);
  }

  __shared__ float4 sh4[H][VL];
  if (eg == 0) sh4[wave][fl] = tot;
  __syncthreads();
  if (threadIdx.x < VL) {
    float4 v = sh4[0][threadIdx.x];
#pragma unroll
    for (int hh = 1; hh < H; ++hh) {
      float4 u = sh4[hh][threadIdx.x];
      v.x += u.x; v.y += u.y; v.z += u.z; v.w += u.w;
    }
    const float sc = 1.0f / H;
    v.x *= sc; v.y *= sc; v.z *= sc; v.w *= sc;
    if (RELU) {
      v.x = fmaxf(v.x, 0.f); v.y = fmaxf(v.y, 0.f);
      v.z = fmaxf(v.z, 0.f); v.w = fmaxf(v.w, 0.f);
    }
    if (base) {
      float4 bv = *(const float4*)&base[(size_t)n * F + threadIdx.x * 4];
      v.x += bv.x; v.y += bv.y; v.z += bv.z; v.w += bv.w;
    }
    *(float4*)&outf[(size_t)n * F + threadIdx.x * 4] = v;
  }
}

template <int H, int F, bool RELU>
__global__ __launch_bounds__(256) void agg_kernel(
    const float* __restrict__ h, const float* __restrict__ el, const float* __restrict__ er,
    const int* __restrict__ ptr, const int* __restrict__ srcs,
    const float* __restrict__ base, float* __restrict__ outf) {
  agg_dev<H, F, RELU>(blockIdx.x, h, el, er, ptr, srcs, base, outf);
}

// Batched agg: 3 instances (mu s0, mu s1, logvar), grid = (N, 3).
struct AggB3 {
  const float* h[3]; const float* el[3]; const float* er[3]; float* out[3];
};
__global__ __launch_bounds__(128) void agg_b3_kernel(
    AggB3 a, const int* __restrict__ ptr, const int* __restrict__ srcs) {
  const int inst = blockIdx.y;
  agg_dev<2, 32, false>(blockIdx.x, a.h[inst], a.el[inst], a.er[inst],
                        ptr, srcs, nullptr, a.out[inst]);
}

// ---------------- adj = mean_s sigmoid(z1[s] @ z2[s]^T) ----------------
// 512 threads, tile 128x128, 8 rows x 4 cols per thread. Conflict-free LDS
// staging (transposed scalar writes) and contiguous float4 fragment reads.
__global__ __launch_bounds__(512) void adj_kernel(const float* __restrict__ mu,
                                                  float* __restrict__ out) {
  __shared__ float sA[32][128];  // [d][i_local]
  __shared__ float sB[32][128];  // [d][j_local]
  const int jb = blockIdx.x * 128;
  const int ib = blockIdx.y * 128;
  const int tid = threadIdx.x;
  const int ty = tid >> 5;   // 0..15: row group (quad-split: ty*4 and 64+ty*4)
  const int tx = tid & 31;   // 0..31: col quad (tx*4)

  float res[8][4];
#pragma unroll
  for (int i = 0; i < 8; ++i)
#pragma unroll
    for (int j = 0; j < 4; ++j) res[i][j] = 0.f;

  for (int s = 0; s < 2; ++s) {
    __syncthreads();
#pragma unroll
    for (int it = 0; it < 2; ++it) {
      int idx = tid + it * 512;
      int dg = idx >> 7, row = idx & 127;   // dg: 0..7 (float4 group of d)
      int gi = ib + row;
      int gj = jb + row;
      float4 va = {0.f, 0.f, 0.f, 0.f}, vb = {0.f, 0.f, 0.f, 0.f};
      if (gi < NB1) va = *(const float4*)&mu[((size_t)s * N_ + gi) * 32 + dg * 4];
      if (gj < NB1) vb = *(const float4*)&mu[((size_t)s * N_ + NB1 + gj) * 32 + dg * 4];
      sA[dg * 4 + 0][row] = va.x; sA[dg * 4 + 1][row] = va.y;
      sA[dg * 4 + 2][row] = va.z; sA[dg * 4 + 3][row] = va.w;
      sB[dg * 4 + 0][row] = vb.x; sB[dg * 4 + 1][row] = vb.y;
      sB[dg * 4 + 2][row] = vb.z; sB[dg * 4 + 3][row] = vb.w;
    }
    __syncthreads();

    float acc[8][4];
#pragma unroll
    for (int i = 0; i < 8; ++i)
#pragma unroll
      for (int j = 0; j < 4; ++j) acc[i][j] = 0.f;
#pragma unroll 8
    for (int k = 0; k < 32; ++k) {
      float a[8], b[4];
      *(float4*)&a[0] = *(const float4*)&sA[k][ty * 4];
      *(float4*)&a[4] = *(const float4*)&sA[k][64 + ty * 4];
      *(float4*)&b[0] = *(const float4*)&sB[k][tx * 4];
#pragma unroll
      for (int i = 0; i < 8; ++i)
#pragma unroll
        for (int j = 0; j < 4; ++j) acc[i][j] = fmaf(a[i], b[j], acc[i][j]);
    }
#pragma unroll
    for (int i = 0; i < 8; ++i)
#pragma unroll
      for (int j = 0; j < 4; ++j) res[i][j] += sigmoidf_(acc[i][j]);
  }

  const bool fullc = (jb + 128) <= NB1;
#pragma unroll
  for (int i = 0; i < 8; ++i) {
    int row = ib + ((i < 4) ? (ty * 4 + i) : (64 + ty * 4 + (i - 4)));
    if (row < NB1) {
      int col = jb + tx * 4;
      if (fullc) {
        float4 p;
        p.x = 0.5f * res[i][0]; p.y = 0.5f * res[i][1];
        p.z = 0.5f * res[i][2]; p.w = 0.5f * res[i][3];
        *(float4*)&out[(size_t)row * NB1 + col] = p;
      } else {
#pragma unroll
        for (int j = 0; j < 4; ++j) {
          if (col + j < NB1) out[(size_t)row * NB1 + col + j] = 0.5f * res[i][j];
        }
      }
    }
  }
}

__global__ void rk2_kernel(const float* __restrict__ rk_lgt, float* __restrict__ out) {
  int i = threadIdx.x;
  if (i < 32) out[i] = sigmoidf_(rk_lgt[i]);
}

// ---------------- host ----------------
static inline size_t align256(size_t x) { return (x + 255) & ~(size_t)255; }

extern "C" void kernel_launch(void* const* d_in, const int* in_sizes, int n_in,
                              void* d_out, int out_size, void* d_ws, size_t ws_size,
                              hipStream_t stream) {
  (void)in_sizes; (void)n_in; (void)out_size; (void)d_ws; (void)ws_size;
  const float* x      = (const float*)d_in[0];
  const float* noise  = (const float*)d_in[1];
  const float* W1     = (const float*)d_in[2];
  const float* al1    = (const float*)d_in[3];
  const float* ar1    = (const float*)d_in[4];
  const float* We     = (const float*)d_in[5];
  const float* ale    = (const float*)d_in[6];
  const float* are    = (const float*)d_in[7];
  const float* W2     = (const float*)d_in[8];
  const float* al2    = (const float*)d_in[9];
  const float* ar2    = (const float*)d_in[10];
  const float* W3     = (const float*)d_in[11];
  const float* al3    = (const float*)d_in[12];
  const float* ar3    = (const float*)d_in[13];
  const float* rk_lgt = (const float*)d_in[14];
  const int*   src    = (const int*)d_in[15];
  const int*   dst    = (const int*)d_in[16];

  float* out_adj    = (float*)d_out;                       // (1,6000,6000)
  float* out_mu     = out_adj + (size_t)NB1 * NB1;         // (2,20000,32) @ 36,000,000
  float* out_logvar = out_mu + (size_t)2 * N_ * 32;        // (20000,32)   @ 37,280,000
  float* out_rk2    = out_logvar + (size_t)N_ * 32;        // (1,32)       @ 37,920,000

  // Scratch in the f32 adj region (144 MB; we use ~84.2 MB), dead before adj.
  char* sc = (char*)d_out;
  size_t off = 0;
  int*   ptr     = (int*)(sc + off);   off += align256((size_t)R_ * (N_ + 1) * 4);      //   240 KB
  int*   csums   = (int*)(sc + off);   off += align256((size_t)R_ * NCH * 4);           //     tiny
  int*   csr_src = (int*)(sc + off);   off += align256((size_t)R_ * E_ * 4);            //  2.40 MB
  float* el      = (float*)(sc + off); off += align256((size_t)R_ * N_ * 4 * 4);        //  0.96 MB
  float* er      = (float*)(sc + off); off += align256((size_t)R_ * N_ * 4 * 4);        //  0.96 MB
  float* el3     = (float*)(sc + off); off += align256((size_t)3 * R_ * N_ * 2 * 4);    //  1.44 MB
  float* er3     = (float*)(sc + off); off += align256((size_t)3 * R_ * N_ * 2 * 4);    //  1.44 MB
  float* hx      = (float*)(sc + off); off += align256((size_t)N_ * 64 * 4);            //  5.12 MB
  float* h1      = (float*)(sc + off); off += align256((size_t)2 * N_ * 64 * 4);        // 10.24 MB
  float* h       = (float*)(sc + off); off += align256((size_t)R_ * N_ * 256 * 4);      // 61.44 MB
  // total ~84.2 MB < 144 MB (f32 adj region)
  // counts/fill alias the h region (dead after CSR build; h written later)
  int* counts = (int*)(void*)h;
  int* fill   = (int*)(void*)((char*)(void*)h + align256((size_t)R_ * N_ * 4));
  // hM3 (3 x R x N x 64 f32 = 46.08 MB) aliases h (61.44 MB; h dead after
  // the last layer-1 agg). el3/er3 are DEDICATED (1.44 MB each; the R3/R4
  // bug was aliasing them onto the 0.96 MB el/er regions).
  float* hM3 = h;

  // ---- CSR (dst shared by all 6 rgat calls) ----
  hipMemsetAsync(counts, 0, (size_t)R_ * N_ * 4, stream);
  hipMemsetAsync(fill, 0, (size_t)R_ * N_ * 4, stream);
  int eblocks = (R_ * E_ + 255) / 256;
  hist_kernel<<<eblocks, 256, 0, stream>>>(dst, counts);
  scan_partial_kernel<<<dim3(NCH, R_), SCAN_CH, 0, stream>>>(counts, ptr, csums);
  scan_sums_kernel<<<1, 64, 0, stream>>>(csums, ptr);
  scan_add_kernel<<<dim3(NCH, R_), SCAN_CH, 0, stream>>>(csums, ptr);
  scatter_kernel<<<eblocks, 256, 0, stream>>>(src, dst, ptr, fill, csr_src);

  const dim3 g256((N_ + 63) / 64, 4, R_);

  // hiddenx = rgat(x, W1, al1, ar1, relu) -> hx (f32)
  gemm_el_kernel<128, 256, 4, 64><<<g256, 256, 0, stream>>>(x, W1, al1, ar1, h, el, er);
  agg_kernel<4, 64, true><<<N_, 256, 0, stream>>>(h, el, er, ptr, csr_src, nullptr, hx);

  // hidden1[s] = hiddenx + rgat(noise[s], We, ale, are, relu) -> h1 (f32)
  for (int s = 0; s < 2; ++s) {
    gemm_el_kernel<64, 256, 4, 64><<<g256, 256, 0, stream>>>(
        noise + (size_t)s * N_ * 64, We, ale, are, h, el, er);
    agg_kernel<4, 64, true><<<N_, 256, 0, stream>>>(
        h, el, er, ptr, csr_src, hx, h1 + (size_t)s * N_ * 64);
  }

  // Batched mu[s] (s=0,1) + logvar layers: one gemm dispatch, one agg dispatch.
  GemmB3 ga;
  AggB3  aa;
  const float* As[3]  = {h1, h1 + (size_t)N_ * 64, hx};
  const float* Ws[3]  = {W2, W2, W3};
  const float* als[3] = {al2, al2, al3};
  const float* ars[3] = {ar2, ar2, ar3};
  float* outs[3] = {out_mu, out_mu + (size_t)N_ * 32, out_logvar};
  for (int i = 0; i < 3; ++i) {
    ga.A[i]  = As[i];  ga.W[i]  = Ws[i]; ga.al[i] = als[i]; ga.ar[i] = ars[i];
    ga.h[i]  = hM3 + (size_t)i * R_ * N_ * 64;
    ga.el[i] = el3 + (size_t)i * R_ * N_ * 2;
    ga.er[i] = er3 + (size_t)i * R_ * N_ * 2;
    aa.h[i]  = ga.h[i];
    aa.el[i] = ga.el[i];
    aa.er[i] = ga.er[i];
    aa.out[i] = outs[i];
  }
  gemm_el_b3_kernel<64, 64, 2, 32><<<dim3((N_ + 63) / 64, 1, 3 * R_), 256, 0, stream>>>(ga);
  agg_b3_kernel<<<dim3(N_, 3), 128, 0, stream>>>(aa, ptr, csr_src);

  rk2_kernel<<<1, 32, 0, stream>>>(rk_lgt, out_rk2);

  // adj: reads out_mu (disjoint range), overwrites the adj-region scratch.
  adj_kernel<<<dim3((NB1 + 127) / 128, (NB1 + 127) / 128), 512, 0, stream>>>(out_mu, out_adj);
}

// Round 6
// 939.051 us; speedup vs baseline: 1.5669x; 1.0342x over previous
//
#include <hip/hip_runtime.h>
#include <hip/hip_bf16.h>

// RGAT pipeline for MI355X. Inputs f32, OUTPUTS f32. Scratch (~84.2 MB) lives
// in d_out's f32 adj region (144 MB), all dead before adj_kernel, which reads
// mu from out_mu (disjoint from the adj range it writes). d_ws/d_in untouched.
//
// R1: agg flash-style online-softmax, vectorized multi-edge float4 gather.
// R2: adj 512-thr 8x4 blocking, conflict-free LDS.
// R3/R4 FAILED: el3/er3 under-allocation collided with er3[0]/hx.
// R5: dedicated el3/er3; 3-phase CSR scan; batched mu/mu/logvar layers.
// R6: agg_dev software-pipelined across relations (fast path deg<=64 all r):
//     hoisted ptr/er/sp/el loads for all 3 relations, interleaved 3-wide
//     butterflies (12 stages x3 ILP vs 3x12 serial), interleaved gathers
//     (raccv[3], ~9 loads in flight). Per-relation FP op sequence and
//     accumulation order bit-identical to R5; slow path = R5 loop verbatim.
//     launch_bounds min-waves=8 caps VGPR at 64 (32 waves/CU).

static constexpr int N_  = 20000;
static constexpr int R_  = 3;
static constexpr int E_  = 200000;
static constexpr int NB1 = 6000;   // N1 == N2 == 6000

__device__ __forceinline__ float sigmoidf_(float x) {
  return 1.0f / (1.0f + __expf(-x));
}

// ---------------- CSR build ----------------
__global__ void hist_kernel(const int* __restrict__ dst, int* __restrict__ counts) {
  int i = blockIdx.x * blockDim.x + threadIdx.x;
  if (i >= R_ * E_) return;
  int r = i / E_;
  atomicAdd(&counts[r * N_ + dst[i]], 1);
}

static constexpr int SCAN_CH = 1024;
static constexpr int NCH = (N_ + SCAN_CH - 1) / SCAN_CH;  // 20

// Phase A: per-1024-chunk local exclusive scan + chunk totals.
__global__ __launch_bounds__(1024) void scan_partial_kernel(
    const int* __restrict__ counts, int* __restrict__ ptr, int* __restrict__ csums) {
  const int r = blockIdx.y, c = blockIdx.x, tid = threadIdx.x;
  __shared__ int buf[SCAN_CH];
  const int i = c * SCAN_CH + tid;
  const int v = (i < N_) ? counts[r * N_ + i] : 0;
  buf[tid] = v;
  __syncthreads();
  for (int off = 1; off < SCAN_CH; off <<= 1) {
    int t = (tid >= off) ? buf[tid - off] : 0;
    __syncthreads();
    buf[tid] += t;
    __syncthreads();
  }
  if (i < N_) ptr[r * (N_ + 1) + i] = buf[tid] - v;  // local exclusive
  if (tid == SCAN_CH - 1) csums[r * NCH + c] = buf[tid];
}

// Phase B: tiny serial scan of chunk totals (R_ threads, 20 entries each).
__global__ void scan_sums_kernel(int* __restrict__ csums, int* __restrict__ ptr) {
  int r = threadIdx.x;
  if (r < R_) {
    int acc = 0;
    for (int c = 0; c < NCH; ++c) {
      int t = csums[r * NCH + c];
      csums[r * NCH + c] = acc;
      acc += t;
    }
    ptr[r * (N_ + 1) + N_] = acc;
  }
}

// Phase C: add chunk bases.
__global__ __launch_bounds__(1024) void scan_add_kernel(
    const int* __restrict__ csums, int* __restrict__ ptr) {
  const int r = blockIdx.y, c = blockIdx.x, tid = threadIdx.x;
  const int i = c * SCAN_CH + tid;
  if (i < N_) ptr[r * (N_ + 1) + i] += csums[r * NCH + c];
}

__global__ void scatter_kernel(const int* __restrict__ src, const int* __restrict__ dst,
                               const int* __restrict__ ptr, int* __restrict__ fill,
                               int* __restrict__ csrc) {
  int i = blockIdx.x * blockDim.x + threadIdx.x;
  if (i >= R_ * E_) return;
  int r = i / E_;
  int d = dst[i];
  int pos = ptr[r * (N_ + 1) + d] + atomicAdd(&fill[r * N_ + d], 1);
  csrc[r * E_ + pos] = src[i];
}

// ---------------- GEMM + fused attention-logit epilogue ----------------
// h[r][n][HF] = A[n][:] @ W[r][:][:] (f32); el/er[r][n][hh] = sum_f h*al/ar.
// 256 threads = 16x16, tile 64 nodes x 64 cols, 4x4 register blocking.
template <int DIN, int HF, int H, int F>
__device__ __forceinline__ void gemm_el_dev(
    const int r, const float* __restrict__ A, const float* __restrict__ W,
    const float* __restrict__ al, const float* __restrict__ ar,
    float* __restrict__ h, float* __restrict__ el, float* __restrict__ er) {
  __shared__ float sAT[64][68];  // [k][node]
  __shared__ float sW[64][68];   // [k][col]
  const int nb  = blockIdx.x * 64;
  const int cg  = blockIdx.y;    // 64-col group
  const int tid = threadIdx.x;
  const int ty  = tid >> 4, tx = tid & 15;

  float acc[4][4];
#pragma unroll
  for (int i = 0; i < 4; ++i)
#pragma unroll
    for (int j = 0; j < 4; ++j) acc[i][j] = 0.f;

  for (int k0 = 0; k0 < DIN; k0 += 64) {
    for (int idx = tid; idx < 4096; idx += 256) {
      int nl = idx >> 6, kk = idx & 63;
      int n = nb + nl;
      sAT[kk][nl] = (n < N_) ? A[(size_t)n * DIN + k0 + kk] : 0.f;
    }
    for (int idx = tid; idx < 4096; idx += 256) {
      int kk = idx >> 6, cl = idx & 63;
      sW[kk][cl] = W[((size_t)r * DIN + k0 + kk) * HF + cg * 64 + cl];
    }
    __syncthreads();
#pragma unroll 8
    for (int kk = 0; kk < 64; ++kk) {
      const float4 a4 = *(const float4*)&sAT[kk][ty * 4];
      const float4 w4 = *(const float4*)&sW[kk][tx * 4];
      const float a[4] = {a4.x, a4.y, a4.z, a4.w};
      const float w[4] = {w4.x, w4.y, w4.z, w4.w};
#pragma unroll
      for (int i = 0; i < 4; ++i)
#pragma unroll
        for (int j = 0; j < 4; ++j) acc[i][j] = fmaf(a[i], w[j], acc[i][j]);
    }
    __syncthreads();
  }

  // store h (float4 per row)
  const int c0 = cg * 64 + tx * 4;
#pragma unroll
  for (int i = 0; i < 4; ++i) {
    int n = nb + ty * 4 + i;
    if (n < N_) {
      float4 v; v.x = acc[i][0]; v.y = acc[i][1]; v.z = acc[i][2]; v.w = acc[i][3];
      *(float4*)&h[((size_t)r * N_ + n) * HF + c0] = v;
    }
  }

  // fused el/er: reduce over f within head via shuffles (group width G = F/4)
  const int hh = c0 / F;
  const int f0 = c0 % F;
  float al4[4], ar4[4];
#pragma unroll
  for (int j = 0; j < 4; ++j) {
    al4[j] = al[((size_t)r * H + hh) * F + f0 + j];
    ar4[j] = ar[((size_t)r * H + hh) * F + f0 + j];
  }
  float elp[4], erp[4];
#pragma unroll
  for (int i = 0; i < 4; ++i) {
    elp[i] = acc[i][0] * al4[0] + acc[i][1] * al4[1] + acc[i][2] * al4[2] + acc[i][3] * al4[3];
    erp[i] = acc[i][0] * ar4[0] + acc[i][1] * ar4[1] + acc[i][2] * ar4[2] + acc[i][3] * ar4[3];
  }
  constexpr int G = F / 4;  // tx-threads per head: 16 (F=64) or 8 (F=32)
#pragma unroll
  for (int off = G / 2; off >= 1; off >>= 1) {
#pragma unroll
    for (int i = 0; i < 4; ++i) {
      elp[i] += __shfl_down(elp[i], off, G);
      erp[i] += __shfl_down(erp[i], off, G);
    }
  }
  if ((tx & (G - 1)) == 0) {
#pragma unroll
    for (int i = 0; i < 4; ++i) {
      int n = nb + ty * 4 + i;
      if (n < N_) {
        el[((size_t)r * N_ + n) * H + hh] = elp[i];
        er[((size_t)r * N_ + n) * H + hh] = erp[i];
      }
    }
  }
}

template <int DIN, int HF, int H, int F>
__global__ __launch_bounds__(256) void gemm_el_kernel(
    const float* __restrict__ A, const float* __restrict__ W,
    const float* __restrict__ al, const float* __restrict__ ar,
    float* __restrict__ h, float* __restrict__ el, float* __restrict__ er) {
  gemm_el_dev<DIN, HF, H, F>(blockIdx.z, A, W, al, ar, h, el, er);
}

// Batched variant: 3 instances (mu s0, mu s1, logvar), grid.z = 3*R_.
struct GemmB3 {
  const float* A[3]; const float* W[3]; const float* al[3]; const float* ar[3];
  float* h[3]; float* el[3]; float* er[3];
};
template <int DIN, int HF, int H, int F>
__global__ __launch_bounds__(256) void gemm_el_b3_kernel(GemmB3 a) {
  const int inst = blockIdx.z / R_;
  const int r    = blockIdx.z % R_;
  gemm_el_dev<DIN, HF, H, F>(r, a.A[inst], a.W[inst], a.al[inst], a.ar[inst],
                             a.h[inst], a.el[inst], a.er[inst]);
}

// ---------------- Per-destination edge softmax + aggregation ----------------
// One block per node; wave = head. Fast path (deg<=64 for all relations,
// which always holds at avg degree 10): all three relations' ptr/er/sp/el
// loads hoisted and issued together, butterflies interleaved 3-wide,
// gathers interleaved (raccv[3]). FP op sequence per relation and the
// cross-relation accumulation order are identical to the R5-verified code;
// deg==0 relations contribute exactly +0.0. Slow path = R5 loop verbatim.
template <int H, int F, bool RELU>
__device__ __forceinline__ void agg_dev(
    const int n, const float* __restrict__ h, const float* __restrict__ el,
    const float* __restrict__ er, const int* __restrict__ ptr,
    const int* __restrict__ srcs, const float* __restrict__ base,
    float* __restrict__ outf) {
  constexpr int VL  = F / 4;    // lanes per edge-row (float4 granules): 16 or 8
  constexpr int EPG = 64 / VL;  // edges per wave-iteration: 4 or 8
  const int wave = threadIdx.x >> 6;   // = head
  const int lane = threadIdx.x & 63;
  const int eg   = lane / VL;          // edge slot within iteration
  const int fl   = lane % VL;          // float4 index within row

  float4 tot = {0.f, 0.f, 0.f, 0.f};

  // hoisted ptr loads (independent across relations)
  int p0v[R_], degv[R_];
#pragma unroll
  for (int r = 0; r < R_; ++r) {
    p0v[r]  = ptr[r * (N_ + 1) + n];
    degv[r] = ptr[r * (N_ + 1) + n + 1] - p0v[r];
  }

  bool fast = true;
#pragma unroll
  for (int r = 0; r < R_; ++r) fast &= (degv[r] <= 64);

  if (__builtin_expect(fast, 1)) {
    // ---- fast path: single chunk per relation, fully pipelined ----
    float ervv[R_];
#pragma unroll
    for (int r = 0; r < R_; ++r)
      ervv[r] = er[((size_t)r * N_ + n) * H + wave];

    int sv[R_];
#pragma unroll
    for (int r = 0; r < R_; ++r)
      sv[r] = (lane < degv[r]) ? srcs[(size_t)r * E_ + p0v[r] + lane] : 0;

    float ev[R_];
#pragma unroll
    for (int r = 0; r < R_; ++r) {
      float e = -3.0e38f;
      if (lane < degv[r]) {
        e = el[((size_t)r * N_ + sv[r]) * H + wave] + ervv[r];
        e = (e > 0.f) ? e : 0.2f * e;
      }
      ev[r] = e;
    }

    // interleaved max butterflies (3 independent chains)
    float mv[R_];
#pragma unroll
    for (int r = 0; r < R_; ++r) mv[r] = ev[r];
#pragma unroll
    for (int off = 32; off >= 1; off >>= 1) {
#pragma unroll
      for (int r = 0; r < R_; ++r)
        mv[r] = fmaxf(mv[r], __shfl_xor(mv[r], off, 64));
    }

    // weights (exp(e - m); padded lanes -> exactly 0; deg==0 -> all 1 but
    // racc stays 0 so the relation contributes +0.0)
    float wv[R_];
#pragma unroll
    for (int r = 0; r < R_; ++r) wv[r] = __expf(ev[r] - mv[r]);

    // interleaved wsum butterflies
    float wsv[R_];
#pragma unroll
    for (int r = 0; r < R_; ++r) wsv[r] = wv[r];
#pragma unroll
    for (int off = 32; off >= 1; off >>= 1) {
#pragma unroll
      for (int r = 0; r < R_; ++r)
        wsv[r] += __shfl_xor(wsv[r], off, 64);
    }

    // interleaved gathers
    float4 raccv[R_];
#pragma unroll
    for (int r = 0; r < R_; ++r) raccv[r] = {0.f, 0.f, 0.f, 0.f};
    int kmaxv[R_];
#pragma unroll
    for (int r = 0; r < R_; ++r) kmaxv[r] = (degv[r] + EPG - 1) / EPG;
    int kmax_all = 0;
#pragma unroll
    for (int r = 0; r < R_; ++r) kmax_all = max(kmax_all, kmaxv[r]);

    for (int k = 0; k < kmax_all; ++k) {
      const int i2 = eg + k * EPG;  // < 64 always
#pragma unroll
      for (int r = 0; r < R_; ++r) {
        if (k < kmaxv[r]) {
          const int   s2 = __shfl(sv[r], i2, 64);
          const float w2 = __shfl(wv[r], i2, 64);
          const float4 hv =
              *(const float4*)&h[((size_t)r * N_ + s2) * (H * F) + wave * F + fl * 4];
          raccv[r].x = fmaf(w2, hv.x, raccv[r].x);
          raccv[r].y = fmaf(w2, hv.y, raccv[r].y);
          raccv[r].z = fmaf(w2, hv.z, raccv[r].z);
          raccv[r].w = fmaf(w2, hv.w, raccv[r].w);
        }
      }
    }

    // accumulate in relation order (identical to serial version)
#pragma unroll
    for (int r = 0; r < R_; ++r) {
      const float inv = 1.0f / (wsv[r] + 1e-16f);
      tot.x = fmaf(raccv[r].x, inv, tot.x);
      tot.y = fmaf(raccv[r].y, inv, tot.y);
      tot.z = fmaf(raccv[r].z, inv, tot.z);
      tot.w = fmaf(raccv[r].w, inv, tot.w);
    }
  } else {
    // ---- slow path: R5-verified chunked online softmax, verbatim ----
    for (int r = 0; r < R_; ++r) {
      const int p0  = p0v[r];
      const int deg = degv[r];
      if (deg == 0) continue;
      const int* sp = srcs + (size_t)r * E_ + p0;
      const float erv = er[((size_t)r * N_ + n) * H + wave];

      float m = -3.0e38f, dsum = 0.f;
      float4 racc = {0.f, 0.f, 0.f, 0.f};

      for (int b0 = 0; b0 < deg; b0 += 64) {
        const int cnt = min(64, deg - b0);
        int   s = 0;
        float e = -3.0e38f;
        if (lane < cnt) {
          s = sp[b0 + lane];
          e = el[((size_t)r * N_ + s) * H + wave] + erv;
          e = (e > 0.f) ? e : 0.2f * e;
        }
        float mloc = e;
#pragma unroll
        for (int off = 32; off >= 1; off >>= 1)
          mloc = fmaxf(mloc, __shfl_xor(mloc, off, 64));
        const float mnew  = fmaxf(m, mloc);
        const float scale = __expf(m - mnew);
        const float w = __expf(e - mnew);
        float wsum = w;
#pragma unroll
        for (int off = 32; off >= 1; off >>= 1)
          wsum += __shfl_xor(wsum, off, 64);
        dsum = fmaf(dsum, scale, wsum);
        racc.x *= scale; racc.y *= scale; racc.z *= scale; racc.w *= scale;
        m = mnew;

        const int kmax = (cnt + EPG - 1) / EPG;
        for (int k = 0; k < kmax; ++k) {
          const int i2 = eg + k * EPG;
          const int   s2 = __shfl(s, i2, 64);
          const float w2 = __shfl(w, i2, 64);
          const float4 hv =
              *(const float4*)&h[((size_t)r * N_ + s2) * (H * F) + wave * F + fl * 4];
          racc.x = fmaf(w2, hv.x, racc.x);
          racc.y = fmaf(w2, hv.y, racc.y);
          racc.z = fmaf(w2, hv.z, racc.z);
          racc.w = fmaf(w2, hv.w, racc.w);
        }
      }
      const float inv = 1.0f / (dsum + 1e-16f);
      tot.x = fmaf(racc.x, inv, tot.x);
      tot.y = fmaf(racc.y, inv, tot.y);
      tot.z = fmaf(racc.z, inv, tot.z);
      tot.w = fmaf(racc.w, inv, tot.w);
    }
  }

  // reduce across edge-groups (xor butterfly over offsets VL..32)
#pragma unroll
  for (int off = VL; off < 64; off <<= 1) {
    tot.x += __shfl_xor(tot.x, off, 64);
    tot.y += __shfl_xor(tot.y, off, 64);
    tot.z += __shfl_xor(tot.z, off, 64);
    tot.w += __shfl_xor(tot.w, off, 64);
  }

  __shared__ float4 sh4[H][VL];
  if (eg == 0) sh4[wave][fl] = tot;
  __syncthreads();
  if (threadIdx.x < VL) {
    float4 v = sh4[0][threadIdx.x];
#pragma unroll
    for (int hh = 1; hh < H; ++hh) {
      float4 u = sh4[hh][threadIdx.x];
      v.x += u.x; v.y += u.y; v.z += u.z; v.w += u.w;
    }
    const float sc = 1.0f / H;
    v.x *= sc; v.y *= sc; v.z *= sc; v.w *= sc;
    if (RELU) {
      v.x = fmaxf(v.x, 0.f); v.y = fmaxf(v.y, 0.f);
      v.z = fmaxf(v.z, 0.f); v.w = fmaxf(v.w, 0.f);
    }
    if (base) {
      float4 bv = *(const float4*)&base[(size_t)n * F + threadIdx.x * 4];
      v.x += bv.x; v.y += bv.y; v.z += bv.z; v.w += bv.w;
    }
    *(float4*)&outf[(size_t)n * F + threadIdx.x * 4] = v;
  }
}

template <int H, int F, bool RELU>
__global__ __launch_bounds__(256, 8) void agg_kernel(
    const float* __restrict__ h, const float* __restrict__ el, const float* __restrict__ er,
    const int* __restrict__ ptr, const int* __restrict__ srcs,
    const float* __restrict__ base, float* __restrict__ outf) {
  agg_dev<H, F, RELU>(blockIdx.x, h, el, er, ptr, srcs, base, outf);
}

// Batched agg: 3 instances (mu s0, mu s1, logvar), grid = (N, 3).
struct AggB3 {
  const float* h[3]; const float* el[3]; const float* er[3]; float* out[3];
};
__global__ __launch_bounds__(128, 8) void agg_b3_kernel(
    AggB3 a, const int* __restrict__ ptr, const int* __restrict__ srcs) {
  const int inst = blockIdx.y;
  agg_dev<2, 32, false>(blockIdx.x, a.h[inst], a.el[inst], a.er[inst],
                        ptr, srcs, nullptr, a.out[inst]);
}

// ---------------- adj = mean_s sigmoid(z1[s] @ z2[s]^T) ----------------
// 512 threads, tile 128x128, 8 rows x 4 cols per thread. Conflict-free LDS
// staging (transposed scalar writes) and contiguous float4 fragment reads.
__global__ __launch_bounds__(512) void adj_kernel(const float* __restrict__ mu,
                                                  float* __restrict__ out) {
  __shared__ float sA[32][128];  // [d][i_local]
  __shared__ float sB[32][128];  // [d][j_local]
  const int jb = blockIdx.x * 128;
  const int ib = blockIdx.y * 128;
  const int tid = threadIdx.x;
  const int ty = tid >> 5;   // 0..15: row group (quad-split: ty*4 and 64+ty*4)
  const int tx = tid & 31;   // 0..31: col quad (tx*4)

  float res[8][4];
#pragma unroll
  for (int i = 0; i < 8; ++i)
#pragma unroll
    for (int j = 0; j < 4; ++j) res[i][j] = 0.f;

  for (int s = 0; s < 2; ++s) {
    __syncthreads();
#pragma unroll
    for (int it = 0; it < 2; ++it) {
      int idx = tid + it * 512;
      int dg = idx >> 7, row = idx & 127;   // dg: 0..7 (float4 group of d)
      int gi = ib + row;
      int gj = jb + row;
      float4 va = {0.f, 0.f, 0.f, 0.f}, vb = {0.f, 0.f, 0.f, 0.f};
      if (gi < NB1) va = *(const float4*)&mu[((size_t)s * N_ + gi) * 32 + dg * 4];
      if (gj < NB1) vb = *(const float4*)&mu[((size_t)s * N_ + NB1 + gj) * 32 + dg * 4];
      sA[dg * 4 + 0][row] = va.x; sA[dg * 4 + 1][row] = va.y;
      sA[dg * 4 + 2][row] = va.z; sA[dg * 4 + 3][row] = va.w;
      sB[dg * 4 + 0][row] = vb.x; sB[dg * 4 + 1][row] = vb.y;
      sB[dg * 4 + 2][row] = vb.z; sB[dg * 4 + 3][row] = vb.w;
    }
    __syncthreads();

    float acc[8][4];
#pragma unroll
    for (int i = 0; i < 8; ++i)
#pragma unroll
      for (int j = 0; j < 4; ++j) acc[i][j] = 0.f;
#pragma unroll 8
    for (int k = 0; k < 32; ++k) {
      float a[8], b[4];
      *(float4*)&a[0] = *(const float4*)&sA[k][ty * 4];
      *(float4*)&a[4] = *(const float4*)&sA[k][64 + ty * 4];
      *(float4*)&b[0] = *(const float4*)&sB[k][tx * 4];
#pragma unroll
      for (int i = 0; i < 8; ++i)
#pragma unroll
        for (int j = 0; j < 4; ++j) acc[i][j] = fmaf(a[i], b[j], acc[i][j]);
    }
#pragma unroll
    for (int i = 0; i < 8; ++i)
#pragma unroll
      for (int j = 0; j < 4; ++j) res[i][j] += sigmoidf_(acc[i][j]);
  }

  const bool fullc = (jb + 128) <= NB1;
#pragma unroll
  for (int i = 0; i < 8; ++i) {
    int row = ib + ((i < 4) ? (ty * 4 + i) : (64 + ty * 4 + (i - 4)));
    if (row < NB1) {
      int col = jb + tx * 4;
      if (fullc) {
        float4 p;
        p.x = 0.5f * res[i][0]; p.y = 0.5f * res[i][1];
        p.z = 0.5f * res[i][2]; p.w = 0.5f * res[i][3];
        *(float4*)&out[(size_t)row * NB1 + col] = p;
      } else {
#pragma unroll
        for (int j = 0; j < 4; ++j) {
          if (col + j < NB1) out[(size_t)row * NB1 + col + j] = 0.5f * res[i][j];
        }
      }
    }
  }
}

__global__ void rk2_kernel(const float* __restrict__ rk_lgt, float* __restrict__ out) {
  int i = threadIdx.x;
  if (i < 32) out[i] = sigmoidf_(rk_lgt[i]);
}

// ---------------- host ----------------
static inline size_t align256(size_t x) { return (x + 255) & ~(size_t)255; }

extern "C" void kernel_launch(void* const* d_in, const int* in_sizes, int n_in,
                              void* d_out, int out_size, void* d_ws, size_t ws_size,
                              hipStream_t stream) {
  (void)in_sizes; (void)n_in; (void)out_size; (void)d_ws; (void)ws_size;
  const float* x      = (const float*)d_in[0];
  const float* noise  = (const float*)d_in[1];
  const float* W1     = (const float*)d_in[2];
  const float* al1    = (const float*)d_in[3];
  const float* ar1    = (const float*)d_in[4];
  const float* We     = (const float*)d_in[5];
  const float* ale    = (const float*)d_in[6];
  const float* are    = (const float*)d_in[7];
  const float* W2     = (const float*)d_in[8];
  const float* al2    = (const float*)d_in[9];
  const float* ar2    = (const float*)d_in[10];
  const float* W3     = (const float*)d_in[11];
  const float* al3    = (const float*)d_in[12];
  const float* ar3    = (const float*)d_in[13];
  const float* rk_lgt = (const float*)d_in[14];
  const int*   src    = (const int*)d_in[15];
  const int*   dst    = (const int*)d_in[16];

  float* out_adj    = (float*)d_out;                       // (1,6000,6000)
  float* out_mu     = out_adj + (size_t)NB1 * NB1;         // (2,20000,32) @ 36,000,000
  float* out_logvar = out_mu + (size_t)2 * N_ * 32;        // (20000,32)   @ 37,280,000
  float* out_rk2    = out_logvar + (size_t)N_ * 32;        // (1,32)       @ 37,920,000

  // Scratch in the f32 adj region (144 MB; we use ~84.2 MB), dead before adj.
  char* sc = (char*)d_out;
  size_t off = 0;
  int*   ptr     = (int*)(sc + off);   off += align256((size_t)R_ * (N_ + 1) * 4);      //   240 KB
  int*   csums   = (int*)(sc + off);   off += align256((size_t)R_ * NCH * 4);           //     tiny
  int*   csr_src = (int*)(sc + off);   off += align256((size_t)R_ * E_ * 4);            //  2.40 MB
  float* el      = (float*)(sc + off); off += align256((size_t)R_ * N_ * 4 * 4);        //  0.96 MB
  float* er      = (float*)(sc + off); off += align256((size_t)R_ * N_ * 4 * 4);        //  0.96 MB
  float* el3     = (float*)(sc + off); off += align256((size_t)3 * R_ * N_ * 2 * 4);    //  1.44 MB
  float* er3     = (float*)(sc + off); off += align256((size_t)3 * R_ * N_ * 2 * 4);    //  1.44 MB
  float* hx      = (float*)(sc + off); off += align256((size_t)N_ * 64 * 4);            //  5.12 MB
  float* h1      = (float*)(sc + off); off += align256((size_t)2 * N_ * 64 * 4);        // 10.24 MB
  float* h       = (float*)(sc + off); off += align256((size_t)R_ * N_ * 256 * 4);      // 61.44 MB
  // total ~84.2 MB < 144 MB (f32 adj region)
  // counts/fill alias the h region (dead after CSR build; h written later)
  int* counts = (int*)(void*)h;
  int* fill   = (int*)(void*)((char*)(void*)h + align256((size_t)R_ * N_ * 4));
  // hM3 (3 x R x N x 64 f32 = 46.08 MB) aliases h (61.44 MB; h dead after
  // the last layer-1 agg). el3/er3 are DEDICATED (1.44 MB each; the R3/R4
  // bug was aliasing them onto the 0.96 MB el/er regions).
  float* hM3 = h;

  // ---- CSR (dst shared by all 6 rgat calls) ----
  hipMemsetAsync(counts, 0, (size_t)R_ * N_ * 4, stream);
  hipMemsetAsync(fill, 0, (size_t)R_ * N_ * 4, stream);
  int eblocks = (R_ * E_ + 255) / 256;
  hist_kernel<<<eblocks, 256, 0, stream>>>(dst, counts);
  scan_partial_kernel<<<dim3(NCH, R_), SCAN_CH, 0, stream>>>(counts, ptr, csums);
  scan_sums_kernel<<<1, 64, 0, stream>>>(csums, ptr);
  scan_add_kernel<<<dim3(NCH, R_), SCAN_CH, 0, stream>>>(csums, ptr);
  scatter_kernel<<<eblocks, 256, 0, stream>>>(src, dst, ptr, fill, csr_src);

  const dim3 g256((N_ + 63) / 64, 4, R_);

  // hiddenx = rgat(x, W1, al1, ar1, relu) -> hx (f32)
  gemm_el_kernel<128, 256, 4, 64><<<g256, 256, 0, stream>>>(x, W1, al1, ar1, h, el, er);
  agg_kernel<4, 64, true><<<N_, 256, 0, stream>>>(h, el, er, ptr, csr_src, nullptr, hx);

  // hidden1[s] = hiddenx + rgat(noise[s], We, ale, are, relu) -> h1 (f32)
  for (int s = 0; s < 2; ++s) {
    gemm_el_kernel<64, 256, 4, 64><<<g256, 256, 0, stream>>>(
        noise + (size_t)s * N_ * 64, We, ale, are, h, el, er);
    agg_kernel<4, 64, true><<<N_, 256, 0, stream>>>(
        h, el, er, ptr, csr_src, hx, h1 + (size_t)s * N_ * 64);
  }

  // Batched mu[s] (s=0,1) + logvar layers: one gemm dispatch, one agg dispatch.
  GemmB3 ga;
  AggB3  aa;
  const float* As[3]  = {h1, h1 + (size_t)N_ * 64, hx};
  const float* Ws[3]  = {W2, W2, W3};
  const float* als[3] = {al2, al2, al3};
  const float* ars[3] = {ar2, ar2, ar3};
  float* outs[3] = {out_mu, out_mu + (size_t)N_ * 32, out_logvar};
  for (int i = 0; i < 3; ++i) {
    ga.A[i]  = As[i];  ga.W[i]  = Ws[i]; ga.al[i] = als[i]; ga.ar[i] = ars[i];
    ga.h[i]  = hM3 + (size_t)i * R_ * N_ * 64;
    ga.el[i] = el3 + (size_t)i * R_ * N_ * 2;
    ga.er[i] = er3 + (size_t)i * R_ * N_ * 2;
    aa.h[i]  = ga.h[i];
    aa.el[i] = ga.el[i];
    aa.er[i] = ga.er[i];
    aa.out[i] = outs[i];
  }
  gemm_el_b3_kernel<64, 64, 2, 32><<<dim3((N_ + 63) / 64, 1, 3 * R_), 256, 0, stream>>>(ga);
  agg_b3_kernel<<<dim3(N_, 3), 128, 0, stream>>>(aa, ptr, csr_src);

  rk2_kernel<<<1, 32, 0, stream>>>(rk_lgt, out_rk2);

  // adj: reads out_mu (disjoint range), overwrites the adj-region scratch.
  adj_kernel<<<dim3((NB1 + 127) / 128, (NB1 + 127) / 128), 512, 0, stream>>>(out_mu, out_adj);
}